// Round 3
// baseline (2043.022 us; speedup 1.0000x reference)
//
#include <hip/hip_runtime.h>
#include <hip/hip_bf16.h>

#define N_NODES 100000
#define N_EDGES 1000000
#define CH 128
#define NCLS 3

__device__ __forceinline__ float bf2f(unsigned short u) {
    return __uint_as_float(((unsigned int)u) << 16);
}

__device__ __forceinline__ int edge_at(const void* e, int is64, long long i) {
    if (is64) return (int)((const long long*)e)[i];
    return ((const int*)e)[i];
}

// Load scalar float from tensor that is either f32 (isbf=0) or bf16 (isbf=1).
__device__ __forceinline__ float ldf(const void* p, int isbf, size_t i) {
    if (isbf) return bf2f(((const unsigned short*)p)[i]);
    return ((const float*)p)[i];
}

// Load 4 consecutive floats.
__device__ __forceinline__ void ldf4(const void* p, int isbf, size_t i, float* o) {
    if (isbf) {
        ushort4 u = *(const ushort4*)((const unsigned short*)p + i);
        o[0] = bf2f(u.x); o[1] = bf2f(u.y); o[2] = bf2f(u.z); o[3] = bf2f(u.w);
    } else {
        float4 v = *(const float4*)((const float*)p + i);
        o[0] = v.x; o[1] = v.y; o[2] = v.z; o[3] = v.w;
    }
}

// Detect whether edge_index is int64 (odd int32 words all zero) or int32.
__global__ void k_detect_edge(const void* __restrict__ e, int* __restrict__ flag) {
    int lane = threadIdx.x;  // 64 threads
    int v = ((const int*)e)[2 * lane + 1];
    unsigned long long b = __ballot(v != 0);
    if (lane == 0) *flag = (b == 0ULL) ? 1 : 0;
}

// Detect whether float tensors are bf16-packed (1) or f32 (0).
__global__ void k_detect_dtype(const unsigned int* __restrict__ p, int* __restrict__ isbf) {
    int lane = threadIdx.x;  // 64 threads
    unsigned int u = p[lane];
    int e = (u >> 7) & 0xff;  // exponent field of low-half bf16
    int sane = (e == 0) || (e >= 100 && e <= 154);
    unsigned long long b = __ballot(sane);
    if (lane == 0) *isbf = (__popcll(b) >= 48) ? 1 : 0;
}

__global__ void k_zero(float* __restrict__ p, int n) {
    int i = blockIdx.x * blockDim.x + threadIdx.x;
    if (i < n) p[i] = 0.0f;
}

__global__ void k_count(const void* __restrict__ e, const int* __restrict__ eflag,
                        float* __restrict__ cnt) {
    int i = blockIdx.x * blockDim.x + threadIdx.x;
    if (i >= N_EDGES) return;
    int is64 = *eflag;
    int dst = edge_at(e, is64, (long long)N_EDGES + i);
    atomicAdd(&cnt[dst], 1.0f);
}

// One wave per edge; lane handles 2 channels. force_f32: feat is our own f32 buffer.
__global__ void k_scatter(const void* __restrict__ e, const int* __restrict__ eflag,
                          const int* __restrict__ dtf, int force_f32,
                          const void* __restrict__ feat, float* __restrict__ agg) {
    long long gt = (long long)blockIdx.x * blockDim.x + threadIdx.x;
    int wv = (int)(gt >> 6);
    int lane = (int)(gt & 63);
    if (wv >= N_EDGES) return;
    int is64 = *eflag;
    int isbf = force_f32 ? 0 : *dtf;
    int src = edge_at(e, is64, wv);
    int dst = edge_at(e, is64, (long long)N_EDGES + wv);
    float v0, v1;
    if (isbf) {
        unsigned int u = ((const unsigned int*)feat)[(size_t)src * (CH / 2) + lane];
        v0 = bf2f((unsigned short)(u & 0xffffu));
        v1 = bf2f((unsigned short)(u >> 16));
    } else {
        float2 f = ((const float2*)feat)[(size_t)src * (CH / 2) + lane];
        v0 = f.x;
        v1 = f.y;
    }
    float* a = agg + (size_t)dst * CH + lane * 2;
    atomicAdd(a, v0);
    atomicAdd(a + 1, v1);
}

// out[i,:] = relu( (agg[i,:] @ wl) / max(cnt[i],1) + bias + x2[i,:] @ wr )
// BM=64, BN=128(all), BK=16, 256 threads, 4x8 micro-tile per thread.
__global__ __launch_bounds__(256) void k_gemm(
    const float* __restrict__ agg, const void* __restrict__ x2, int x2_force_f32,
    const void* __restrict__ wl, const void* __restrict__ wr,
    const void* __restrict__ bias, const float* __restrict__ cnt,
    const int* __restrict__ dtf, float* __restrict__ out) {
    __shared__ float As[16][68];
    __shared__ float Bs[16][132];
    const int t = threadIdx.x;
    const int tx = t & 15;   // col group: 8 cols each
    const int ty = t >> 4;   // row group: 4 rows each
    const int row0 = blockIdx.x * 64;
    const int lr = t >> 2;   // A-load row 0..63
    const int lc = t & 3;    // A-load float4 group 0..3
    const int isbf = *dtf;
    const int x2bf = x2_force_f32 ? 0 : isbf;

    float acc[4][8];
#pragma unroll
    for (int i = 0; i < 4; i++)
#pragma unroll
        for (int j = 0; j < 8; j++) acc[i][j] = 0.0f;

    for (int phase = 0; phase < 2; ++phase) {
        const void* W = phase ? wr : wl;
        for (int k0 = 0; k0 < CH; k0 += 16) {
            // ---- global loads into registers ----
            float av[4] = {0.f, 0.f, 0.f, 0.f};
            int grow = row0 + lr;
            if (grow < N_NODES) {
                if (phase == 0) {
                    float4 v = *(const float4*)(agg + (size_t)grow * CH + k0 + lc * 4);
                    av[0] = v.x; av[1] = v.y; av[2] = v.z; av[3] = v.w;
                } else {
                    ldf4(x2, x2bf, (size_t)grow * CH + k0 + lc * 4, av);
                }
            }
            float bv[2][4];
#pragma unroll
            for (int i = 0; i < 2; i++) {
                int idx = t + i * 256;
                int kk = idx >> 5, n4 = idx & 31;
                ldf4(W, isbf, (size_t)(k0 + kk) * CH + n4 * 4, bv[i]);
            }
            __syncthreads();
            // ---- stage to LDS ----
#pragma unroll
            for (int j = 0; j < 4; j++) As[lc * 4 + j][lr] = av[j];
#pragma unroll
            for (int i = 0; i < 2; i++) {
                int idx = t + i * 256;
                int kk = idx >> 5, n4 = idx & 31;
                *(float4*)&Bs[kk][n4 * 4] =
                    make_float4(bv[i][0], bv[i][1], bv[i][2], bv[i][3]);
            }
            __syncthreads();
            // ---- compute ----
#pragma unroll
            for (int k = 0; k < 16; k++) {
                float a[4];
                *(float4*)a = *(const float4*)&As[k][ty * 4];
                float b[8];
                *(float4*)&b[0] = *(const float4*)&Bs[k][tx * 8];
                *(float4*)&b[4] = *(const float4*)&Bs[k][tx * 8 + 4];
#pragma unroll
                for (int i = 0; i < 4; i++)
#pragma unroll
                    for (int j = 0; j < 8; j++) acc[i][j] += a[i] * b[j];
            }
        }
        if (phase == 0) {
#pragma unroll
            for (int i = 0; i < 4; i++) {
                int grow = row0 + ty * 4 + i;
                float c = (grow < N_NODES) ? cnt[grow] : 1.0f;
                float rinv = 1.0f / fmaxf(c, 1.0f);
#pragma unroll
                for (int j = 0; j < 8; j++) acc[i][j] *= rinv;
            }
        }
    }
    // epilogue: + bias, relu, store
    float bj[8];
#pragma unroll
    for (int j = 0; j < 8; j++) bj[j] = ldf(bias, isbf, tx * 8 + j);
#pragma unroll
    for (int i = 0; i < 4; i++) {
        int grow = row0 + ty * 4 + i;
        if (grow < N_NODES) {
            float o[8];
#pragma unroll
            for (int j = 0; j < 8; j++) o[j] = fmaxf(acc[i][j] + bj[j], 0.0f);
            *(float4*)(out + (size_t)grow * CH + tx * 8) = *(float4*)&o[0];
            *(float4*)(out + (size_t)grow * CH + tx * 8 + 4) = *(float4*)&o[4];
        }
    }
}

// logits = h @ w_cls + b_cls ; one wave per node, lane = 2 channels. f32 output.
__global__ void k_cls(const float* __restrict__ h, const void* __restrict__ wc,
                      const void* __restrict__ bc, const int* __restrict__ dtf,
                      float* __restrict__ out) {
    long long gt = (long long)blockIdx.x * blockDim.x + threadIdx.x;
    int node = (int)(gt >> 6);
    int lane = (int)(gt & 63);
    if (node >= N_NODES) return;
    int isbf = *dtf;
    float2 hv = ((const float2*)h)[(size_t)node * (CH / 2) + lane];
    int c0 = lane * 2;
    float a[NCLS];
#pragma unroll
    for (int j = 0; j < NCLS; j++)
        a[j] = hv.x * ldf(wc, isbf, (size_t)c0 * NCLS + j) +
               hv.y * ldf(wc, isbf, (size_t)(c0 + 1) * NCLS + j);
#pragma unroll
    for (int off = 32; off > 0; off >>= 1) {
#pragma unroll
        for (int j = 0; j < NCLS; j++) a[j] += __shfl_down(a[j], off);
    }
    if (lane == 0) {
#pragma unroll
        for (int j = 0; j < NCLS; j++)
            out[(size_t)node * NCLS + j] = a[j] + ldf(bc, isbf, j);
    }
}

extern "C" void kernel_launch(void* const* d_in, const int* in_sizes, int n_in,
                              void* d_out, int out_size, void* d_ws, size_t ws_size,
                              hipStream_t stream) {
    const void* x = d_in[0];
    const void* eidx = d_in[1];
    const void* w_l1 = d_in[2];
    const void* b_l1 = d_in[3];
    const void* w_r1 = d_in[4];
    const void* w_l2 = d_in[5];
    const void* b_l2 = d_in[6];
    const void* w_r2 = d_in[7];
    const void* w_cls = d_in[8];
    const void* b_cls = d_in[9];

    char* w = (char*)d_ws;
    int* eflag = (int*)w;
    int* dtf = (int*)(w + 64);
    float* cnt = (float*)(w + 1024);
    float* A = (float*)(w + 401408);                                  // 51.2 MB
    float* B = (float*)(w + 401408 + (size_t)N_NODES * CH * 4);       // 51.2 MB

    const int nfeat = N_NODES * CH;  // 12.8M

    hipLaunchKernelGGL(k_detect_edge, dim3(1), dim3(64), 0, stream, eidx, eflag);
    hipLaunchKernelGGL(k_detect_dtype, dim3(1), dim3(64), 0, stream,
                       (const unsigned int*)x, dtf);
    hipLaunchKernelGGL(k_zero, dim3((N_NODES + 255) / 256), dim3(256), 0, stream, cnt, N_NODES);
    hipLaunchKernelGGL(k_zero, dim3(nfeat / 256), dim3(256), 0, stream, A, nfeat);
    hipLaunchKernelGGL(k_count, dim3((N_EDGES + 255) / 256), dim3(256), 0, stream,
                       eidx, eflag, cnt);
    // layer 1
    hipLaunchKernelGGL(k_scatter, dim3(N_EDGES * 64 / 256), dim3(256), 0, stream,
                       eidx, eflag, dtf, 0, x, A);
    hipLaunchKernelGGL(k_gemm, dim3((N_NODES + 63) / 64), dim3(256), 0, stream,
                       A, x, 0, w_l1, w_r1, b_l1, cnt, dtf, B);
    // layer 2
    hipLaunchKernelGGL(k_zero, dim3(nfeat / 256), dim3(256), 0, stream, A, nfeat);
    hipLaunchKernelGGL(k_scatter, dim3(N_EDGES * 64 / 256), dim3(256), 0, stream,
                       eidx, eflag, dtf, 1, B, A);
    hipLaunchKernelGGL(k_gemm, dim3((N_NODES + 63) / 64), dim3(256), 0, stream,
                       A, B, 1, w_l2, w_r2, b_l2, cnt, dtf, A);
    // classifier
    hipLaunchKernelGGL(k_cls, dim3(N_NODES * 64 / 256), dim3(256), 0, stream,
                       A, w_cls, b_cls, dtf, (float*)d_out);
}

// Round 4
// 596.622 us; speedup vs baseline: 3.4243x; 3.4243x over previous
//
#include <hip/hip_runtime.h>
#include <hip/hip_bf16.h>

#define N_NODES 100000
#define N_EDGES 1000000
#define CH 128
#define NCLS 3
#define SCAN_B 1024
#define SCAN_NB ((N_NODES + SCAN_B - 1) / SCAN_B)  // 98

__device__ __forceinline__ float bf2f(unsigned short u) {
    return __uint_as_float(((unsigned int)u) << 16);
}

__device__ __forceinline__ int edge_at(const void* e, int is64, long long i) {
    if (is64) return (int)((const long long*)e)[i];
    return ((const int*)e)[i];
}

__device__ __forceinline__ float ldf(const void* p, int isbf, size_t i) {
    if (isbf) return bf2f(((const unsigned short*)p)[i]);
    return ((const float*)p)[i];
}

__device__ __forceinline__ void ldf4(const void* p, int isbf, size_t i, float* o) {
    if (isbf) {
        ushort4 u = *(const ushort4*)((const unsigned short*)p + i);
        o[0] = bf2f(u.x); o[1] = bf2f(u.y); o[2] = bf2f(u.z); o[3] = bf2f(u.w);
    } else {
        float4 v = *(const float4*)((const float*)p + i);
        o[0] = v.x; o[1] = v.y; o[2] = v.z; o[3] = v.w;
    }
}

// --- runtime dtype sniffers (wave-uniform branch cost only) ---
__global__ void k_detect_edge(const void* __restrict__ e, int* __restrict__ flag) {
    int lane = threadIdx.x;  // 64 threads
    int v = ((const int*)e)[2 * lane + 1];
    unsigned long long b = __ballot(v != 0);
    if (lane == 0) *flag = (b == 0ULL) ? 1 : 0;
}

__global__ void k_detect_dtype(const unsigned int* __restrict__ p, int* __restrict__ isbf) {
    int lane = threadIdx.x;  // 64 threads
    unsigned int u = p[lane];
    int e = (u >> 7) & 0xff;
    int sane = (e == 0) || (e >= 100 && e <= 154);
    unsigned long long b = __ballot(sane);
    if (lane == 0) *isbf = (__popcll(b) >= 48) ? 1 : 0;
}

__global__ void k_zero_i(int* __restrict__ p, int n) {
    int i = blockIdx.x * blockDim.x + threadIdx.x;
    if (i < n) p[i] = 0;
}

__global__ void k_count(const void* __restrict__ e, const int* __restrict__ eflag,
                        int* __restrict__ cnt) {
    int i = blockIdx.x * blockDim.x + threadIdx.x;
    if (i >= N_EDGES) return;
    int is64 = *eflag;
    int dst = edge_at(e, is64, (long long)N_EDGES + i);
    atomicAdd(&cnt[dst], 1);
}

// --- 3-phase exclusive scan over 100k degree counts ---
__global__ void k_scan1(const int* __restrict__ cnt, int* __restrict__ excl,
                        int* __restrict__ bsum) {
    __shared__ int s[SCAN_B];
    int tid = threadIdx.x;
    int gid = blockIdx.x * SCAN_B + tid;
    int v = (gid < N_NODES) ? cnt[gid] : 0;
    s[tid] = v;
    __syncthreads();
    for (int off = 1; off < SCAN_B; off <<= 1) {
        int t = (tid >= off) ? s[tid - off] : 0;
        __syncthreads();
        s[tid] += t;
        __syncthreads();
    }
    if (gid < N_NODES) excl[gid] = s[tid] - v;
    if (tid == SCAN_B - 1) bsum[blockIdx.x] = s[tid];
}

__global__ void k_scan2(int* __restrict__ bsum) {  // SCAN_NB <= 128
    __shared__ int s[128];
    int tid = threadIdx.x;
    int v = (tid < SCAN_NB) ? bsum[tid] : 0;
    s[tid] = v;
    __syncthreads();
    for (int off = 1; off < 128; off <<= 1) {
        int t = (tid >= off) ? s[tid - off] : 0;
        __syncthreads();
        s[tid] += t;
        __syncthreads();
    }
    if (tid < SCAN_NB) bsum[tid] = s[tid] - v;  // exclusive
}

__global__ void k_scan3(const int* __restrict__ excl, const int* __restrict__ bsum,
                        int* __restrict__ row_start) {
    int gid = blockIdx.x * SCAN_B + threadIdx.x;
    if (gid < N_NODES) row_start[gid] = excl[gid] + bsum[blockIdx.x];
    if (gid == 0) row_start[N_NODES] = N_EDGES;
}

// --- bucket edges into CSR (1M cheap int atomics, once per launch) ---
__global__ void k_bucket(const void* __restrict__ e, const int* __restrict__ eflag,
                         const int* __restrict__ row_start, int* __restrict__ cursor,
                         int* __restrict__ csr_src) {
    int i = blockIdx.x * blockDim.x + threadIdx.x;
    if (i >= N_EDGES) return;
    int is64 = *eflag;
    int src = edge_at(e, is64, i);
    int dst = edge_at(e, is64, (long long)N_EDGES + i);
    int pos = atomicAdd(&cursor[dst], 1);
    csr_src[row_start[dst] + pos] = src;
}

// --- gather aggregation: one wave per node, lane = 2 channels; writes MEAN ---
__global__ __launch_bounds__(256) void k_agg(
    const int* __restrict__ row_start, const int* __restrict__ csr_src,
    const int* __restrict__ dtf, int force_f32,
    const void* __restrict__ feat, float* __restrict__ agg) {
    long long gt = (long long)blockIdx.x * blockDim.x + threadIdx.x;
    int node = (int)(gt >> 6);
    int lane = (int)(gt & 63);
    if (node >= N_NODES) return;
    int isbf = force_f32 ? 0 : *dtf;
    int beg = row_start[node];
    int end = row_start[node + 1];
    float a0 = 0.f, a1 = 0.f;
    int e = beg;
    // 2-way unroll for load-latency overlap
    for (; e + 1 < end; e += 2) {
        int s0 = csr_src[e], s1 = csr_src[e + 1];
        float v0, v1, w0, w1;
        if (isbf) {
            unsigned int u0 = ((const unsigned int*)feat)[(size_t)s0 * (CH / 2) + lane];
            unsigned int u1 = ((const unsigned int*)feat)[(size_t)s1 * (CH / 2) + lane];
            v0 = bf2f((unsigned short)(u0 & 0xffffu)); v1 = bf2f((unsigned short)(u0 >> 16));
            w0 = bf2f((unsigned short)(u1 & 0xffffu)); w1 = bf2f((unsigned short)(u1 >> 16));
        } else {
            float2 f0 = ((const float2*)feat)[(size_t)s0 * (CH / 2) + lane];
            float2 f1 = ((const float2*)feat)[(size_t)s1 * (CH / 2) + lane];
            v0 = f0.x; v1 = f0.y; w0 = f1.x; w1 = f1.y;
        }
        a0 += v0 + w0;
        a1 += v1 + w1;
    }
    if (e < end) {
        int s0 = csr_src[e];
        if (isbf) {
            unsigned int u0 = ((const unsigned int*)feat)[(size_t)s0 * (CH / 2) + lane];
            a0 += bf2f((unsigned short)(u0 & 0xffffu));
            a1 += bf2f((unsigned short)(u0 >> 16));
        } else {
            float2 f0 = ((const float2*)feat)[(size_t)s0 * (CH / 2) + lane];
            a0 += f0.x;
            a1 += f0.y;
        }
    }
    float rinv = 1.0f / (float)max(end - beg, 1);
    ((float2*)agg)[(size_t)node * (CH / 2) + lane] = make_float2(a0 * rinv, a1 * rinv);
}

// out[i,:] = relu( mean[i,:] @ wl + bias + x2[i,:] @ wr )
// BM=64, BN=128(all), BK=16, 256 threads, 4x8 micro-tile per thread.
__global__ __launch_bounds__(256) void k_gemm(
    const float* __restrict__ mean, const void* __restrict__ x2, int x2_force_f32,
    const void* __restrict__ wl, const void* __restrict__ wr,
    const void* __restrict__ bias, const int* __restrict__ dtf,
    float* __restrict__ out) {
    __shared__ float As[16][68];
    __shared__ float Bs[16][132];
    const int t = threadIdx.x;
    const int tx = t & 15;
    const int ty = t >> 4;
    const int row0 = blockIdx.x * 64;
    const int lr = t >> 2;
    const int lc = t & 3;
    const int isbf = *dtf;
    const int x2bf = x2_force_f32 ? 0 : isbf;

    float acc[4][8];
#pragma unroll
    for (int i = 0; i < 4; i++)
#pragma unroll
        for (int j = 0; j < 8; j++) acc[i][j] = 0.0f;

    for (int phase = 0; phase < 2; ++phase) {
        const void* W = phase ? wr : wl;
        for (int k0 = 0; k0 < CH; k0 += 16) {
            float av[4] = {0.f, 0.f, 0.f, 0.f};
            int grow = row0 + lr;
            if (grow < N_NODES) {
                if (phase == 0) {
                    float4 v = *(const float4*)(mean + (size_t)grow * CH + k0 + lc * 4);
                    av[0] = v.x; av[1] = v.y; av[2] = v.z; av[3] = v.w;
                } else {
                    ldf4(x2, x2bf, (size_t)grow * CH + k0 + lc * 4, av);
                }
            }
            float bv[2][4];
#pragma unroll
            for (int i = 0; i < 2; i++) {
                int idx = t + i * 256;
                int kk = idx >> 5, n4 = idx & 31;
                ldf4(W, isbf, (size_t)(k0 + kk) * CH + n4 * 4, bv[i]);
            }
            __syncthreads();
#pragma unroll
            for (int j = 0; j < 4; j++) As[lc * 4 + j][lr] = av[j];
#pragma unroll
            for (int i = 0; i < 2; i++) {
                int idx = t + i * 256;
                int kk = idx >> 5, n4 = idx & 31;
                *(float4*)&Bs[kk][n4 * 4] =
                    make_float4(bv[i][0], bv[i][1], bv[i][2], bv[i][3]);
            }
            __syncthreads();
#pragma unroll
            for (int k = 0; k < 16; k++) {
                float a[4];
                *(float4*)a = *(const float4*)&As[k][ty * 4];
                float b[8];
                *(float4*)&b[0] = *(const float4*)&Bs[k][tx * 8];
                *(float4*)&b[4] = *(const float4*)&Bs[k][tx * 8 + 4];
#pragma unroll
                for (int i = 0; i < 4; i++)
#pragma unroll
                    for (int j = 0; j < 8; j++) acc[i][j] += a[i] * b[j];
            }
        }
    }
    float bj[8];
#pragma unroll
    for (int j = 0; j < 8; j++) bj[j] = ldf(bias, isbf, tx * 8 + j);
#pragma unroll
    for (int i = 0; i < 4; i++) {
        int grow = row0 + ty * 4 + i;
        if (grow < N_NODES) {
            float o[8];
#pragma unroll
            for (int j = 0; j < 8; j++) o[j] = fmaxf(acc[i][j] + bj[j], 0.0f);
            *(float4*)(out + (size_t)grow * CH + tx * 8) = *(float4*)&o[0];
            *(float4*)(out + (size_t)grow * CH + tx * 8 + 4) = *(float4*)&o[4];
        }
    }
}

// logits = h @ w_cls + b_cls ; one wave per node. f32 output.
__global__ void k_cls(const float* __restrict__ h, const void* __restrict__ wc,
                      const void* __restrict__ bc, const int* __restrict__ dtf,
                      float* __restrict__ out) {
    long long gt = (long long)blockIdx.x * blockDim.x + threadIdx.x;
    int node = (int)(gt >> 6);
    int lane = (int)(gt & 63);
    if (node >= N_NODES) return;
    int isbf = *dtf;
    float2 hv = ((const float2*)h)[(size_t)node * (CH / 2) + lane];
    int c0 = lane * 2;
    float a[NCLS];
#pragma unroll
    for (int j = 0; j < NCLS; j++)
        a[j] = hv.x * ldf(wc, isbf, (size_t)c0 * NCLS + j) +
               hv.y * ldf(wc, isbf, (size_t)(c0 + 1) * NCLS + j);
#pragma unroll
    for (int off = 32; off > 0; off >>= 1) {
#pragma unroll
        for (int j = 0; j < NCLS; j++) a[j] += __shfl_down(a[j], off);
    }
    if (lane == 0) {
#pragma unroll
        for (int j = 0; j < NCLS; j++)
            out[(size_t)node * NCLS + j] = a[j] + ldf(bc, isbf, j);
    }
}

extern "C" void kernel_launch(void* const* d_in, const int* in_sizes, int n_in,
                              void* d_out, int out_size, void* d_ws, size_t ws_size,
                              hipStream_t stream) {
    const void* x = d_in[0];
    const void* eidx = d_in[1];
    const void* w_l1 = d_in[2];
    const void* b_l1 = d_in[3];
    const void* w_r1 = d_in[4];
    const void* w_l2 = d_in[5];
    const void* b_l2 = d_in[6];
    const void* w_r2 = d_in[7];
    const void* w_cls = d_in[8];
    const void* b_cls = d_in[9];

    char* w = (char*)d_ws;
    int* eflag = (int*)w;                       // 4 B
    int* dtf = (int*)(w + 64);                  // 4 B
    int* cnt = (int*)(w + 4096);                // 400000 B
    int* cursor = (int*)(w + 404096);           // 400000 B (contiguous with cnt)
    int* row_start = (int*)(w + 819200);        // 400004 B
    int* excl = (int*)(w + 1310720);            // 400000 B
    int* bsum = (int*)(w + 1769472);            // 512 B
    int* csr_src = (int*)(w + 2097152);         // 4 MB
    float* A = (float*)(w + 8388608);           // 51.2 MB
    float* B = (float*)(w + 62914560);          // 51.2 MB (ends ~112 MB)

    hipLaunchKernelGGL(k_detect_edge, dim3(1), dim3(64), 0, stream, eidx, eflag);
    hipLaunchKernelGGL(k_detect_dtype, dim3(1), dim3(64), 0, stream,
                       (const unsigned int*)x, dtf);
    // zero cnt + cursor (contiguous 200000 ints)
    hipLaunchKernelGGL(k_zero_i, dim3((200000 + 255) / 256), dim3(256), 0, stream,
                       cnt, 200000);
    // CSR build (once; reused by both layers)
    hipLaunchKernelGGL(k_count, dim3((N_EDGES + 255) / 256), dim3(256), 0, stream,
                       eidx, eflag, cnt);
    hipLaunchKernelGGL(k_scan1, dim3(SCAN_NB), dim3(SCAN_B), 0, stream, cnt, excl, bsum);
    hipLaunchKernelGGL(k_scan2, dim3(1), dim3(128), 0, stream, bsum);
    hipLaunchKernelGGL(k_scan3, dim3(SCAN_NB), dim3(SCAN_B), 0, stream,
                       excl, bsum, row_start);
    hipLaunchKernelGGL(k_bucket, dim3((N_EDGES + 255) / 256), dim3(256), 0, stream,
                       eidx, eflag, row_start, cursor, csr_src);
    // layer 1
    hipLaunchKernelGGL(k_agg, dim3(N_NODES * 64 / 256), dim3(256), 0, stream,
                       row_start, csr_src, dtf, 0, x, A);
    hipLaunchKernelGGL(k_gemm, dim3((N_NODES + 63) / 64), dim3(256), 0, stream,
                       A, x, 0, w_l1, w_r1, b_l1, dtf, B);
    // layer 2
    hipLaunchKernelGGL(k_agg, dim3(N_NODES * 64 / 256), dim3(256), 0, stream,
                       row_start, csr_src, dtf, 1, B, A);
    hipLaunchKernelGGL(k_gemm, dim3((N_NODES + 63) / 64), dim3(256), 0, stream,
                       A, B, 1, w_l2, w_r2, b_l2, dtf, A);
    // classifier
    hipLaunchKernelGGL(k_cls, dim3(N_NODES * 64 / 256), dim3(256), 0, stream,
                       A, w_cls, b_cls, dtf, (float*)d_out);
}

// Round 5
// 397.226 us; speedup vs baseline: 5.1432x; 1.5020x over previous
//
#include <hip/hip_runtime.h>
#include <hip/hip_bf16.h>

#define N_NODES 100000
#define N_EDGES 1000000
#define CH 128
#define KTOT 256
#define NCLS 3
#define SCAN_B 1024
#define SCAN_NB ((N_NODES + SCAN_B - 1) / SCAN_B)  // 98

typedef __attribute__((ext_vector_type(8))) short v8s;   // 8 bf16 (A/B frag)
typedef __attribute__((ext_vector_type(4))) float v4f;   // 4 f32 (C/D frag)

__device__ __forceinline__ float bf2f(unsigned short u) {
    return __uint_as_float(((unsigned int)u) << 16);
}

__device__ __forceinline__ unsigned short f2bf(float f) {  // RNE
    unsigned int u = __float_as_uint(f);
    unsigned int r = (u + 0x7fffu + ((u >> 16) & 1u)) >> 16;
    return (unsigned short)r;
}

__device__ __forceinline__ int edge_at(const void* e, int is64, long long i) {
    if (is64) return (int)((const long long*)e)[i];
    return ((const int*)e)[i];
}

__device__ __forceinline__ float ldf(const void* p, int isbf, size_t i) {
    if (isbf) return bf2f(((const unsigned short*)p)[i]);
    return ((const float*)p)[i];
}

// --- runtime dtype sniffers ---
__global__ void k_detect_edge(const void* __restrict__ e, int* __restrict__ flag) {
    int lane = threadIdx.x;  // 64 threads
    int v = ((const int*)e)[2 * lane + 1];
    unsigned long long b = __ballot(v != 0);
    if (lane == 0) *flag = (b == 0ULL) ? 1 : 0;
}

__global__ void k_detect_dtype(const unsigned int* __restrict__ p, int* __restrict__ isbf) {
    int lane = threadIdx.x;  // 64 threads
    unsigned int u = p[lane];
    int e = (u >> 7) & 0xff;
    int sane = (e == 0) || (e >= 100 && e <= 154);
    unsigned long long b = __ballot(sane);
    if (lane == 0) *isbf = (__popcll(b) >= 48) ? 1 : 0;
}

__global__ void k_zero_i(int* __restrict__ p, int n) {
    int i = blockIdx.x * blockDim.x + threadIdx.x;
    if (i < n) p[i] = 0;
}

__global__ void k_count(const void* __restrict__ e, const int* __restrict__ eflag,
                        int* __restrict__ cnt) {
    int i = blockIdx.x * blockDim.x + threadIdx.x;
    if (i >= N_EDGES) return;
    int is64 = *eflag;
    int dst = edge_at(e, is64, (long long)N_EDGES + i);
    atomicAdd(&cnt[dst], 1);
}

// --- 3-phase exclusive scan ---
__global__ void k_scan1(const int* __restrict__ cnt, int* __restrict__ excl,
                        int* __restrict__ bsum) {
    __shared__ int s[SCAN_B];
    int tid = threadIdx.x;
    int gid = blockIdx.x * SCAN_B + tid;
    int v = (gid < N_NODES) ? cnt[gid] : 0;
    s[tid] = v;
    __syncthreads();
    for (int off = 1; off < SCAN_B; off <<= 1) {
        int t = (tid >= off) ? s[tid - off] : 0;
        __syncthreads();
        s[tid] += t;
        __syncthreads();
    }
    if (gid < N_NODES) excl[gid] = s[tid] - v;
    if (tid == SCAN_B - 1) bsum[blockIdx.x] = s[tid];
}

__global__ void k_scan2(int* __restrict__ bsum) {
    __shared__ int s[128];
    int tid = threadIdx.x;
    int v = (tid < SCAN_NB) ? bsum[tid] : 0;
    s[tid] = v;
    __syncthreads();
    for (int off = 1; off < 128; off <<= 1) {
        int t = (tid >= off) ? s[tid - off] : 0;
        __syncthreads();
        s[tid] += t;
        __syncthreads();
    }
    if (tid < SCAN_NB) bsum[tid] = s[tid] - v;
}

__global__ void k_scan3(const int* __restrict__ excl, const int* __restrict__ bsum,
                        int* __restrict__ row_start) {
    int gid = blockIdx.x * SCAN_B + threadIdx.x;
    if (gid < N_NODES) row_start[gid] = excl[gid] + bsum[blockIdx.x];
    if (gid == 0) row_start[N_NODES] = N_EDGES;
}

__global__ void k_bucket(const void* __restrict__ e, const int* __restrict__ eflag,
                         const int* __restrict__ row_start, int* __restrict__ cursor,
                         int* __restrict__ csr_src) {
    int i = blockIdx.x * blockDim.x + threadIdx.x;
    if (i >= N_EDGES) return;
    int is64 = *eflag;
    int src = edge_at(e, is64, i);
    int dst = edge_at(e, is64, (long long)N_EDGES + i);
    int pos = atomicAdd(&cursor[dst], 1);
    csr_src[row_start[dst] + pos] = src;
}

// --- convert x (f32 or bf16) into Abuf cols 128..255 as bf16 ---
__global__ void k_cvt_x(const void* __restrict__ x, const int* __restrict__ dtf,
                        unsigned short* __restrict__ Abuf) {
    int idx = blockIdx.x * blockDim.x + threadIdx.x;  // 3.2M threads, 4 ch each
    if (idx >= N_NODES * CH / 4) return;
    int node = idx >> 5;
    int ch = (idx & 31) * 4;
    int isbf = *dtf;
    unsigned short o[4];
    if (isbf) {
        ushort4 u = *(const ushort4*)((const unsigned short*)x + (size_t)node * CH + ch);
        o[0] = u.x; o[1] = u.y; o[2] = u.z; o[3] = u.w;
    } else {
        float4 v = *(const float4*)((const float*)x + (size_t)node * CH + ch);
        o[0] = f2bf(v.x); o[1] = f2bf(v.y); o[2] = f2bf(v.z); o[3] = f2bf(v.w);
    }
    *(ushort4*)(Abuf + (size_t)node * KTOT + CH + ch) = make_ushort4(o[0], o[1], o[2], o[3]);
}

// --- convert wl/wr (each [128][128]) into WT[n][k] bf16, k<128 from wl, k>=128 from wr ---
__global__ void k_cvt_w(const void* __restrict__ wl, const void* __restrict__ wr,
                        const int* __restrict__ dtf, unsigned short* __restrict__ WT) {
    int i = blockIdx.x * blockDim.x + threadIdx.x;  // 32768
    if (i >= KTOT * CH) return;
    int k = i >> 7;
    int n = i & 127;
    int isbf = *dtf;
    float v = (k < CH) ? ldf(wl, isbf, (size_t)k * CH + n)
                       : ldf(wr, isbf, (size_t)(k - CH) * CH + n);
    WT[(size_t)n * KTOT + k] = f2bf(v);
}

// --- gather-mean aggregation in bf16: one wave per node, lane = 2 ch ---
// gathers rows from gsrc[node][128..255] region, writes mean to gdst[node][0..127]
__global__ __launch_bounds__(256) void k_agg(
    const int* __restrict__ row_start, const int* __restrict__ csr_src,
    const unsigned short* __restrict__ gsrc, unsigned short* __restrict__ gdst) {
    long long gt = (long long)blockIdx.x * blockDim.x + threadIdx.x;
    int node = (int)(gt >> 6);
    int lane = (int)(gt & 63);
    if (node >= N_NODES) return;
    int beg = row_start[node];
    int end = row_start[node + 1];
    float a0 = 0.f, a1 = 0.f;
    int e = beg;
    for (; e + 3 < end; e += 4) {
        int s0 = csr_src[e], s1 = csr_src[e + 1], s2 = csr_src[e + 2], s3 = csr_src[e + 3];
        unsigned int u0 = ((const unsigned int*)(gsrc + (size_t)s0 * KTOT + CH))[lane];
        unsigned int u1 = ((const unsigned int*)(gsrc + (size_t)s1 * KTOT + CH))[lane];
        unsigned int u2 = ((const unsigned int*)(gsrc + (size_t)s2 * KTOT + CH))[lane];
        unsigned int u3 = ((const unsigned int*)(gsrc + (size_t)s3 * KTOT + CH))[lane];
        a0 += bf2f((unsigned short)(u0 & 0xffffu)) + bf2f((unsigned short)(u1 & 0xffffu)) +
              bf2f((unsigned short)(u2 & 0xffffu)) + bf2f((unsigned short)(u3 & 0xffffu));
        a1 += bf2f((unsigned short)(u0 >> 16)) + bf2f((unsigned short)(u1 >> 16)) +
              bf2f((unsigned short)(u2 >> 16)) + bf2f((unsigned short)(u3 >> 16));
    }
    for (; e < end; e++) {
        int s0 = csr_src[e];
        unsigned int u0 = ((const unsigned int*)(gsrc + (size_t)s0 * KTOT + CH))[lane];
        a0 += bf2f((unsigned short)(u0 & 0xffffu));
        a1 += bf2f((unsigned short)(u0 >> 16));
    }
    float rinv = 1.0f / (float)max(end - beg, 1);
    unsigned int packed = (unsigned int)f2bf(a0 * rinv) |
                          ((unsigned int)f2bf(a1 * rinv) << 16);
    ((unsigned int*)(gdst + (size_t)node * KTOT))[lane] = packed;
}

// --- MFMA GEMM: out[m][n] = relu( A[m][0:256] @ WT[n][0:256]^T + bias[n] ), bf16 out ---
// block: 128 rows, 4 waves 2x2, each wave 64x64 via 4x4 subtiles of 16x16x32.
#define LDK 40  // padded LDS k-stride (bf16 elems); 80 B, 16-aligned, 2-way-free frag reads
__global__ __launch_bounds__(256) void k_gemm_mfma(
    const unsigned short* __restrict__ Abuf, const unsigned short* __restrict__ WT,
    const void* __restrict__ bias, const int* __restrict__ dtf,
    unsigned short* __restrict__ out, int out_stride, int out_off) {
    __shared__ unsigned short As[128 * LDK];
    __shared__ unsigned short Bs[128 * LDK];
    const int t = threadIdx.x;
    const int w = t >> 6, l = t & 63;
    const int wx = w & 1, wy = w >> 1;
    const int quad = l >> 4, lrow = l & 15;
    const int row0 = blockIdx.x * 128;
    const int srow = t >> 1, shalf = t & 1;  // staging: row 0..127, 32B half

    v4f acc[4][4];
#pragma unroll
    for (int i = 0; i < 4; i++)
#pragma unroll
        for (int j = 0; j < 4; j++) acc[i][j] = (v4f){0.f, 0.f, 0.f, 0.f};

    for (int k0 = 0; k0 < KTOT; k0 += 32) {
        int ar = row0 + srow;
        if (ar >= N_NODES) ar = N_NODES - 1;  // clamp reads (stores guarded later)
        const uint4* ga = (const uint4*)(Abuf + (size_t)ar * KTOT + k0 + shalf * 16);
        uint4 a0 = ga[0], a1 = ga[1];
        const uint4* gb = (const uint4*)(WT + (size_t)srow * KTOT + k0 + shalf * 16);
        uint4 b0 = gb[0], b1 = gb[1];
        __syncthreads();
        *(uint4*)&As[srow * LDK + shalf * 16] = a0;
        *(uint4*)&As[srow * LDK + shalf * 16 + 8] = a1;
        *(uint4*)&Bs[srow * LDK + shalf * 16] = b0;
        *(uint4*)&Bs[srow * LDK + shalf * 16 + 8] = b1;
        __syncthreads();
        v8s af[4], bfr[4];
#pragma unroll
        for (int mi = 0; mi < 4; mi++)
            af[mi] = *(const v8s*)&As[(wy * 64 + mi * 16 + lrow) * LDK + quad * 8];
#pragma unroll
        for (int ni = 0; ni < 4; ni++)
            bfr[ni] = *(const v8s*)&Bs[(wx * 64 + ni * 16 + lrow) * LDK + quad * 8];
#pragma unroll
        for (int mi = 0; mi < 4; mi++)
#pragma unroll
            for (int ni = 0; ni < 4; ni++)
                acc[mi][ni] = __builtin_amdgcn_mfma_f32_16x16x32_bf16(
                    af[mi], bfr[ni], acc[mi][ni], 0, 0, 0);
    }
    // epilogue: bias + relu + bf16 store. D: row=quad*4+reg, col=lrow (per subtile)
    const int isbf = *dtf;
    float bj[4];
#pragma unroll
    for (int ni = 0; ni < 4; ni++) bj[ni] = ldf(bias, isbf, wx * 64 + ni * 16 + lrow);
#pragma unroll
    for (int mi = 0; mi < 4; mi++) {
#pragma unroll
        for (int r = 0; r < 4; r++) {
            int grow = row0 + wy * 64 + mi * 16 + quad * 4 + r;
            if (grow < N_NODES) {
#pragma unroll
                for (int ni = 0; ni < 4; ni++) {
                    int col = wx * 64 + ni * 16 + lrow;
                    float v = fmaxf(acc[mi][ni][r] + bj[ni], 0.0f);
                    out[(size_t)grow * out_stride + out_off + col] = f2bf(v);
                }
            }
        }
    }
}

// --- classifier: one wave per node, Hf bf16 in, f32 logits out ---
__global__ void k_cls(const unsigned short* __restrict__ h, const void* __restrict__ wc,
                      const void* __restrict__ bc, const int* __restrict__ dtf,
                      float* __restrict__ out) {
    long long gt = (long long)blockIdx.x * blockDim.x + threadIdx.x;
    int node = (int)(gt >> 6);
    int lane = (int)(gt & 63);
    if (node >= N_NODES) return;
    int isbf = *dtf;
    unsigned int hu = ((const unsigned int*)(h + (size_t)node * CH))[lane];
    float h0 = bf2f((unsigned short)(hu & 0xffffu));
    float h1 = bf2f((unsigned short)(hu >> 16));
    int c0 = lane * 2;
    float a[NCLS];
#pragma unroll
    for (int j = 0; j < NCLS; j++)
        a[j] = h0 * ldf(wc, isbf, (size_t)c0 * NCLS + j) +
               h1 * ldf(wc, isbf, (size_t)(c0 + 1) * NCLS + j);
#pragma unroll
    for (int off = 32; off > 0; off >>= 1) {
#pragma unroll
        for (int j = 0; j < NCLS; j++) a[j] += __shfl_down(a[j], off);
    }
    if (lane == 0) {
#pragma unroll
        for (int j = 0; j < NCLS; j++)
            out[(size_t)node * NCLS + j] = a[j] + ldf(bc, isbf, j);
    }
}

extern "C" void kernel_launch(void* const* d_in, const int* in_sizes, int n_in,
                              void* d_out, int out_size, void* d_ws, size_t ws_size,
                              hipStream_t stream) {
    const void* x = d_in[0];
    const void* eidx = d_in[1];
    const void* w_l1 = d_in[2];
    const void* b_l1 = d_in[3];
    const void* w_r1 = d_in[4];
    const void* w_l2 = d_in[5];
    const void* b_l2 = d_in[6];
    const void* w_r2 = d_in[7];
    const void* w_cls = d_in[8];
    const void* b_cls = d_in[9];

    char* w = (char*)d_ws;
    int* eflag = (int*)w;
    int* dtf = (int*)(w + 64);
    int* cnt = (int*)(w + 4096);
    int* cursor = (int*)(w + 404096);
    int* row_start = (int*)(w + 819200);
    int* excl = (int*)(w + 1310720);
    int* bsum = (int*)(w + 1769472);
    int* csr_src = (int*)(w + 2097152);                     // 4 MB
    unsigned short* WT1 = (unsigned short*)(w + 8388608);   // 64 KB
    unsigned short* WT2 = (unsigned short*)(w + 8454144);   // 64 KB
    unsigned short* A1 = (unsigned short*)(w + 9437184);    // [100k][256] bf16 = 51.2 MB
    unsigned short* A2 = (unsigned short*)(w + 60637184);   // 51.2 MB (ends ~111.8 MB)
    unsigned short* Hf = A1;                                // reuse A1 for final features

    hipLaunchKernelGGL(k_detect_edge, dim3(1), dim3(64), 0, stream, eidx, eflag);
    hipLaunchKernelGGL(k_detect_dtype, dim3(1), dim3(64), 0, stream,
                       (const unsigned int*)x, dtf);
    hipLaunchKernelGGL(k_zero_i, dim3((200000 + 255) / 256), dim3(256), 0, stream,
                       cnt, 200000);  // cnt + cursor contiguous
    // CSR build
    hipLaunchKernelGGL(k_count, dim3((N_EDGES + 255) / 256), dim3(256), 0, stream,
                       eidx, eflag, cnt);
    hipLaunchKernelGGL(k_scan1, dim3(SCAN_NB), dim3(SCAN_B), 0, stream, cnt, excl, bsum);
    hipLaunchKernelGGL(k_scan2, dim3(1), dim3(128), 0, stream, bsum);
    hipLaunchKernelGGL(k_scan3, dim3(SCAN_NB), dim3(SCAN_B), 0, stream,
                       excl, bsum, row_start);
    hipLaunchKernelGGL(k_bucket, dim3((N_EDGES + 255) / 256), dim3(256), 0, stream,
                       eidx, eflag, row_start, cursor, csr_src);
    // converts
    hipLaunchKernelGGL(k_cvt_x, dim3(N_NODES * CH / 4 / 256), dim3(256), 0, stream,
                       x, dtf, A1);
    hipLaunchKernelGGL(k_cvt_w, dim3(KTOT * CH / 256), dim3(256), 0, stream,
                       w_l1, w_r1, dtf, WT1);
    hipLaunchKernelGGL(k_cvt_w, dim3(KTOT * CH / 256), dim3(256), 0, stream,
                       w_l2, w_r2, dtf, WT2);
    // layer 1
    hipLaunchKernelGGL(k_agg, dim3(N_NODES * 64 / 256), dim3(256), 0, stream,
                       row_start, csr_src, A1, A1);
    hipLaunchKernelGGL(k_gemm_mfma, dim3((N_NODES + 127) / 128), dim3(256), 0, stream,
                       A1, WT1, b_l1, dtf, A2, KTOT, CH);   // h -> A2 cols 128..255
    // layer 2
    hipLaunchKernelGGL(k_agg, dim3(N_NODES * 64 / 256), dim3(256), 0, stream,
                       row_start, csr_src, A2, A2);
    hipLaunchKernelGGL(k_gemm_mfma, dim3((N_NODES + 127) / 128), dim3(256), 0, stream,
                       A2, WT2, b_l2, dtf, Hf, CH, 0);      // h2 -> Hf [100k][128]
    // classifier
    hipLaunchKernelGGL(k_cls, dim3(N_NODES * 64 / 256), dim3(256), 0, stream,
                       Hf, w_cls, b_cls, dtf, (float*)d_out);
}

// Round 6
// 340.997 us; speedup vs baseline: 5.9913x; 1.1649x over previous
//
#include <hip/hip_runtime.h>
#include <hip/hip_bf16.h>

#define N_NODES 100000
#define N_EDGES 1000000
#define CH 128
#define KTOT 256
#define NCLS 3
#define SCAN_B 1024
#define SCAN_NB ((N_NODES + SCAN_B - 1) / SCAN_B)  // 98

typedef __attribute__((ext_vector_type(8))) short v8s;   // 8 bf16 (A/B frag)
typedef __attribute__((ext_vector_type(4))) float v4f;   // 4 f32 (C/D frag)

__device__ __forceinline__ float bf2f(unsigned short u) {
    return __uint_as_float(((unsigned int)u) << 16);
}

__device__ __forceinline__ unsigned short f2bf(float f) {  // RNE
    unsigned int u = __float_as_uint(f);
    unsigned int r = (u + 0x7fffu + ((u >> 16) & 1u)) >> 16;
    return (unsigned short)r;
}

__device__ __forceinline__ int edge_at(const void* e, int is64, long long i) {
    if (is64) return (int)((const long long*)e)[i];
    return ((const int*)e)[i];
}

__device__ __forceinline__ float ldf(const void* p, int isbf, size_t i) {
    if (isbf) return bf2f(((const unsigned short*)p)[i]);
    return ((const float*)p)[i];
}

__device__ __forceinline__ void acc_u32(unsigned int u, float& a0, float& a1) {
    a0 += bf2f((unsigned short)(u & 0xffffu));
    a1 += bf2f((unsigned short)(u >> 16));
}

// --- runtime dtype sniffers ---
__global__ void k_detect_edge(const void* __restrict__ e, int* __restrict__ flag) {
    int lane = threadIdx.x;  // 64 threads
    int v = ((const int*)e)[2 * lane + 1];
    unsigned long long b = __ballot(v != 0);
    if (lane == 0) *flag = (b == 0ULL) ? 1 : 0;
}

__global__ void k_detect_dtype(const unsigned int* __restrict__ p, int* __restrict__ isbf) {
    int lane = threadIdx.x;  // 64 threads
    unsigned int u = p[lane];
    int e = (u >> 7) & 0xff;
    int sane = (e == 0) || (e >= 100 && e <= 154);
    unsigned long long b = __ballot(sane);
    if (lane == 0) *isbf = (__popcll(b) >= 48) ? 1 : 0;
}

__global__ void k_zero_i(int* __restrict__ p, int n) {
    int i = blockIdx.x * blockDim.x + threadIdx.x;
    if (i < n) p[i] = 0;
}

// count degrees AND record each edge's within-row position (kills bucket atomics)
__global__ void k_count(const void* __restrict__ e, const int* __restrict__ eflag,
                        int* __restrict__ cnt, int* __restrict__ epos) {
    int i = blockIdx.x * blockDim.x + threadIdx.x;
    if (i >= N_EDGES) return;
    int is64 = *eflag;
    int dst = edge_at(e, is64, (long long)N_EDGES + i);
    epos[i] = atomicAdd(&cnt[dst], 1);
}

// --- 3-phase exclusive scan ---
__global__ void k_scan1(const int* __restrict__ cnt, int* __restrict__ excl,
                        int* __restrict__ bsum) {
    __shared__ int s[SCAN_B];
    int tid = threadIdx.x;
    int gid = blockIdx.x * SCAN_B + tid;
    int v = (gid < N_NODES) ? cnt[gid] : 0;
    s[tid] = v;
    __syncthreads();
    for (int off = 1; off < SCAN_B; off <<= 1) {
        int t = (tid >= off) ? s[tid - off] : 0;
        __syncthreads();
        s[tid] += t;
        __syncthreads();
    }
    if (gid < N_NODES) excl[gid] = s[tid] - v;
    if (tid == SCAN_B - 1) bsum[blockIdx.x] = s[tid];
}

__global__ void k_scan2(int* __restrict__ bsum) {
    __shared__ int s[128];
    int tid = threadIdx.x;
    int v = (tid < SCAN_NB) ? bsum[tid] : 0;
    s[tid] = v;
    __syncthreads();
    for (int off = 1; off < 128; off <<= 1) {
        int t = (tid >= off) ? s[tid - off] : 0;
        __syncthreads();
        s[tid] += t;
        __syncthreads();
    }
    if (tid < SCAN_NB) bsum[tid] = s[tid] - v;
}

__global__ void k_scan3(const int* __restrict__ excl, const int* __restrict__ bsum,
                        int* __restrict__ row_start) {
    int gid = blockIdx.x * SCAN_B + threadIdx.x;
    if (gid < N_NODES) row_start[gid] = excl[gid] + bsum[blockIdx.x];
    if (gid == 0) row_start[N_NODES] = N_EDGES;
}

// pure gather->scatter, no atomics, no atomic->store dependency
__global__ void k_bucket(const void* __restrict__ e, const int* __restrict__ eflag,
                         const int* __restrict__ row_start, const int* __restrict__ epos,
                         int* __restrict__ csr_src) {
    int i = blockIdx.x * blockDim.x + threadIdx.x;
    if (i >= N_EDGES) return;
    int is64 = *eflag;
    int src = edge_at(e, is64, i);
    int dst = edge_at(e, is64, (long long)N_EDGES + i);
    csr_src[row_start[dst] + epos[i]] = src;
}

// --- convert x into Abuf cols 128..255 as bf16 ---
__global__ void k_cvt_x(const void* __restrict__ x, const int* __restrict__ dtf,
                        unsigned short* __restrict__ Abuf) {
    int idx = blockIdx.x * blockDim.x + threadIdx.x;  // one thread = 4 ch
    if (idx >= N_NODES * CH / 4) return;
    int node = idx >> 5;
    int ch = (idx & 31) * 4;
    int isbf = *dtf;
    unsigned short o[4];
    if (isbf) {
        ushort4 u = *(const ushort4*)((const unsigned short*)x + (size_t)node * CH + ch);
        o[0] = u.x; o[1] = u.y; o[2] = u.z; o[3] = u.w;
    } else {
        float4 v = *(const float4*)((const float*)x + (size_t)node * CH + ch);
        o[0] = f2bf(v.x); o[1] = f2bf(v.y); o[2] = f2bf(v.z); o[3] = f2bf(v.w);
    }
    *(ushort4*)(Abuf + (size_t)node * KTOT + CH + ch) = make_ushort4(o[0], o[1], o[2], o[3]);
}

// --- convert wl/wr into WT[n][k] bf16 (k<128 wl, k>=128 wr) ---
__global__ void k_cvt_w(const void* __restrict__ wl, const void* __restrict__ wr,
                        const int* __restrict__ dtf, unsigned short* __restrict__ WT) {
    int i = blockIdx.x * blockDim.x + threadIdx.x;  // 32768
    if (i >= KTOT * CH) return;
    int k = i >> 7;
    int n = i & 127;
    int isbf = *dtf;
    float v = (k < CH) ? ldf(wl, isbf, (size_t)k * CH + n)
                       : ldf(wr, isbf, (size_t)(k - CH) * CH + n);
    WT[(size_t)n * KTOT + k] = f2bf(v);
}

// --- gather-mean aggregation: 4 nodes per wave, 16 lanes/node, 8 ch/lane ---
// reads gsrc[*][128..255], writes mean bf16 to gdst[*][0..127]
__global__ __launch_bounds__(256) void k_agg(
    const int* __restrict__ row_start, const int* __restrict__ csr_src,
    const unsigned short* __restrict__ gsrc, unsigned short* __restrict__ gdst) {
    long long gt = (long long)blockIdx.x * blockDim.x + threadIdx.x;
    int node = (int)(gt >> 4);   // quarter-wave per node
    int lane = (int)(gt & 15);   // 16 lanes x 16 B = 256 B row
    if (node >= N_NODES) return;
    int beg = row_start[node];
    int end = row_start[node + 1];
    float a[8];
#pragma unroll
    for (int j = 0; j < 8; j++) a[j] = 0.f;
    int e = beg;
    for (; e + 1 < end; e += 2) {  // 2 edges in flight per node
        int s0 = csr_src[e], s1 = csr_src[e + 1];
        uint4 u0 = *(const uint4*)(gsrc + (size_t)s0 * KTOT + CH + lane * 8);
        uint4 u1 = *(const uint4*)(gsrc + (size_t)s1 * KTOT + CH + lane * 8);
        acc_u32(u0.x, a[0], a[1]); acc_u32(u0.y, a[2], a[3]);
        acc_u32(u0.z, a[4], a[5]); acc_u32(u0.w, a[6], a[7]);
        acc_u32(u1.x, a[0], a[1]); acc_u32(u1.y, a[2], a[3]);
        acc_u32(u1.z, a[4], a[5]); acc_u32(u1.w, a[6], a[7]);
    }
    if (e < end) {
        int s0 = csr_src[e];
        uint4 u0 = *(const uint4*)(gsrc + (size_t)s0 * KTOT + CH + lane * 8);
        acc_u32(u0.x, a[0], a[1]); acc_u32(u0.y, a[2], a[3]);
        acc_u32(u0.z, a[4], a[5]); acc_u32(u0.w, a[6], a[7]);
    }
    float rinv = 1.0f / (float)max(end - beg, 1);
    unsigned int p0 = (unsigned int)f2bf(a[0] * rinv) | ((unsigned int)f2bf(a[1] * rinv) << 16);
    unsigned int p1 = (unsigned int)f2bf(a[2] * rinv) | ((unsigned int)f2bf(a[3] * rinv) << 16);
    unsigned int p2 = (unsigned int)f2bf(a[4] * rinv) | ((unsigned int)f2bf(a[5] * rinv) << 16);
    unsigned int p3 = (unsigned int)f2bf(a[6] * rinv) | ((unsigned int)f2bf(a[7] * rinv) << 16);
    *(uint4*)(gdst + (size_t)node * KTOT + lane * 8) = make_uint4(p0, p1, p2, p3);
}

// --- MFMA GEMM: out = relu(A[m][0:256] @ WT[n][0:256]^T + bias), bf16 out ---
#define LDK 40
__global__ __launch_bounds__(256) void k_gemm_mfma(
    const unsigned short* __restrict__ Abuf, const unsigned short* __restrict__ WT,
    const void* __restrict__ bias, const int* __restrict__ dtf,
    unsigned short* __restrict__ out, int out_stride, int out_off) {
    __shared__ unsigned short As[128 * LDK];
    __shared__ unsigned short Bs[128 * LDK];
    const int t = threadIdx.x;
    const int w = t >> 6, l = t & 63;
    const int wx = w & 1, wy = w >> 1;
    const int quad = l >> 4, lrow = l & 15;
    const int row0 = blockIdx.x * 128;
    const int srow = t >> 1, shalf = t & 1;

    v4f acc[4][4];
#pragma unroll
    for (int i = 0; i < 4; i++)
#pragma unroll
        for (int j = 0; j < 4; j++) acc[i][j] = (v4f){0.f, 0.f, 0.f, 0.f};

    for (int k0 = 0; k0 < KTOT; k0 += 32) {
        int ar = row0 + srow;
        if (ar >= N_NODES) ar = N_NODES - 1;
        const uint4* ga = (const uint4*)(Abuf + (size_t)ar * KTOT + k0 + shalf * 16);
        uint4 a0 = ga[0], a1 = ga[1];
        const uint4* gb = (const uint4*)(WT + (size_t)srow * KTOT + k0 + shalf * 16);
        uint4 b0 = gb[0], b1 = gb[1];
        __syncthreads();
        *(uint4*)&As[srow * LDK + shalf * 16] = a0;
        *(uint4*)&As[srow * LDK + shalf * 16 + 8] = a1;
        *(uint4*)&Bs[srow * LDK + shalf * 16] = b0;
        *(uint4*)&Bs[srow * LDK + shalf * 16 + 8] = b1;
        __syncthreads();
        v8s af[4], bfr[4];
#pragma unroll
        for (int mi = 0; mi < 4; mi++)
            af[mi] = *(const v8s*)&As[(wy * 64 + mi * 16 + lrow) * LDK + quad * 8];
#pragma unroll
        for (int ni = 0; ni < 4; ni++)
            bfr[ni] = *(const v8s*)&Bs[(wx * 64 + ni * 16 + lrow) * LDK + quad * 8];
#pragma unroll
        for (int mi = 0; mi < 4; mi++)
#pragma unroll
            for (int ni = 0; ni < 4; ni++)
                acc[mi][ni] = __builtin_amdgcn_mfma_f32_16x16x32_bf16(
                    af[mi], bfr[ni], acc[mi][ni], 0, 0, 0);
    }
    const int isbf = *dtf;
    float bj[4];
#pragma unroll
    for (int ni = 0; ni < 4; ni++) bj[ni] = ldf(bias, isbf, wx * 64 + ni * 16 + lrow);
#pragma unroll
    for (int mi = 0; mi < 4; mi++) {
#pragma unroll
        for (int r = 0; r < 4; r++) {
            int grow = row0 + wy * 64 + mi * 16 + quad * 4 + r;
            if (grow < N_NODES) {
#pragma unroll
                for (int ni = 0; ni < 4; ni++) {
                    int col = wx * 64 + ni * 16 + lrow;
                    float v = fmaxf(acc[mi][ni][r] + bj[ni], 0.0f);
                    out[(size_t)grow * out_stride + out_off + col] = f2bf(v);
                }
            }
        }
    }
}

// --- classifier: one wave per node, bf16 h in, f32 logits out ---
__global__ void k_cls(const unsigned short* __restrict__ h, const void* __restrict__ wc,
                      const void* __restrict__ bc, const int* __restrict__ dtf,
                      float* __restrict__ out) {
    long long gt = (long long)blockIdx.x * blockDim.x + threadIdx.x;
    int node = (int)(gt >> 6);
    int lane = (int)(gt & 63);
    if (node >= N_NODES) return;
    int isbf = *dtf;
    unsigned int hu = ((const unsigned int*)(h + (size_t)node * CH))[lane];
    float h0 = bf2f((unsigned short)(hu & 0xffffu));
    float h1 = bf2f((unsigned short)(hu >> 16));
    int c0 = lane * 2;
    float a[NCLS];
#pragma unroll
    for (int j = 0; j < NCLS; j++)
        a[j] = h0 * ldf(wc, isbf, (size_t)c0 * NCLS + j) +
               h1 * ldf(wc, isbf, (size_t)(c0 + 1) * NCLS + j);
#pragma unroll
    for (int off = 32; off > 0; off >>= 1) {
#pragma unroll
        for (int j = 0; j < NCLS; j++) a[j] += __shfl_down(a[j], off);
    }
    if (lane == 0) {
#pragma unroll
        for (int j = 0; j < NCLS; j++)
            out[(size_t)node * NCLS + j] = a[j] + ldf(bc, isbf, j);
    }
}

extern "C" void kernel_launch(void* const* d_in, const int* in_sizes, int n_in,
                              void* d_out, int out_size, void* d_ws, size_t ws_size,
                              hipStream_t stream) {
    const void* x = d_in[0];
    const void* eidx = d_in[1];
    const void* w_l1 = d_in[2];
    const void* b_l1 = d_in[3];
    const void* w_r1 = d_in[4];
    const void* w_l2 = d_in[5];
    const void* b_l2 = d_in[6];
    const void* w_r2 = d_in[7];
    const void* w_cls = d_in[8];
    const void* b_cls = d_in[9];

    char* w = (char*)d_ws;
    int* eflag = (int*)w;
    int* dtf = (int*)(w + 64);
    int* cnt = (int*)(w + 4096);                            // 400 KB
    int* row_start = (int*)(w + 405504);                    // 400 KB
    int* excl = (int*)(w + 806912);                         // 400 KB
    int* bsum = (int*)(w + 1207296);                        // 512 B
    int* epos = (int*)(w + 2097152);                        // 4 MB
    int* csr_src = (int*)(w + 6291456);                     // 4 MB
    unsigned short* WT1 = (unsigned short*)(w + 10485760);  // 64 KB
    unsigned short* WT2 = (unsigned short*)(w + 10551296);  // 64 KB
    unsigned short* A1 = (unsigned short*)(w + 11534336);   // 51.2 MB
    unsigned short* A2 = (unsigned short*)(w + 62914560);   // 51.2 MB (ends 114,114,560 — proven fits)
    unsigned short* Hf = A1;

    hipLaunchKernelGGL(k_detect_edge, dim3(1), dim3(64), 0, stream, eidx, eflag);
    hipLaunchKernelGGL(k_detect_dtype, dim3(1), dim3(64), 0, stream,
                       (const unsigned int*)x, dtf);
    hipLaunchKernelGGL(k_zero_i, dim3((N_NODES + 255) / 256), dim3(256), 0, stream,
                       cnt, N_NODES);
    // CSR build
    hipLaunchKernelGGL(k_count, dim3((N_EDGES + 255) / 256), dim3(256), 0, stream,
                       eidx, eflag, cnt, epos);
    hipLaunchKernelGGL(k_scan1, dim3(SCAN_NB), dim3(SCAN_B), 0, stream, cnt, excl, bsum);
    hipLaunchKernelGGL(k_scan2, dim3(1), dim3(128), 0, stream, bsum);
    hipLaunchKernelGGL(k_scan3, dim3(SCAN_NB), dim3(SCAN_B), 0, stream,
                       excl, bsum, row_start);
    hipLaunchKernelGGL(k_bucket, dim3((N_EDGES + 255) / 256), dim3(256), 0, stream,
                       eidx, eflag, row_start, epos, csr_src);
    // converts
    hipLaunchKernelGGL(k_cvt_x, dim3(N_NODES * CH / 4 / 256), dim3(256), 0, stream,
                       x, dtf, A1);
    hipLaunchKernelGGL(k_cvt_w, dim3(KTOT * CH / 256), dim3(256), 0, stream,
                       w_l1, w_r1, dtf, WT1);
    hipLaunchKernelGGL(k_cvt_w, dim3(KTOT * CH / 256), dim3(256), 0, stream,
                       w_l2, w_r2, dtf, WT2);
    // layer 1
    hipLaunchKernelGGL(k_agg, dim3(N_NODES * 16 / 256), dim3(256), 0, stream,
                       row_start, csr_src, A1, A1);
    hipLaunchKernelGGL(k_gemm_mfma, dim3((N_NODES + 127) / 128), dim3(256), 0, stream,
                       A1, WT1, b_l1, dtf, A2, KTOT, CH);
    // layer 2
    hipLaunchKernelGGL(k_agg, dim3(N_NODES * 16 / 256), dim3(256), 0, stream,
                       row_start, csr_src, A2, A2);
    hipLaunchKernelGGL(k_gemm_mfma, dim3((N_NODES + 127) / 128), dim3(256), 0, stream,
                       A2, WT2, b_l2, dtf, Hf, CH, 0);
    // classifier
    hipLaunchKernelGGL(k_cls, dim3(N_NODES * 64 / 256), dim3(256), 0, stream,
                       Hf, w_cls, b_cls, dtf, (float*)d_out);
}

// Round 7
// 340.252 us; speedup vs baseline: 6.0044x; 1.0022x over previous
//
#include <hip/hip_runtime.h>
#include <hip/hip_bf16.h>

#define N_NODES 100000
#define N_EDGES 1000000
#define CH 128
#define KTOT 256
#define NCLS 3
#define SCAN_B 1024
#define SCAN_NB ((N_NODES + SCAN_B - 1) / SCAN_B)  // 98

typedef __attribute__((ext_vector_type(8))) short v8s;   // 8 bf16 (A/B frag)
typedef __attribute__((ext_vector_type(4))) float v4f;   // 4 f32 (C/D frag)

__device__ __forceinline__ float bf2f(unsigned short u) {
    return __uint_as_float(((unsigned int)u) << 16);
}

__device__ __forceinline__ unsigned short f2bf(float f) {  // RNE
    unsigned int u = __float_as_uint(f);
    unsigned int r = (u + 0x7fffu + ((u >> 16) & 1u)) >> 16;
    return (unsigned short)r;
}

__device__ __forceinline__ int edge_at(const void* e, int is64, long long i) {
    if (is64) return (int)((const long long*)e)[i];
    return ((const int*)e)[i];
}

__device__ __forceinline__ float ldf(const void* p, int isbf, size_t i) {
    if (isbf) return bf2f(((const unsigned short*)p)[i]);
    return ((const float*)p)[i];
}

__device__ __forceinline__ void acc_u32(unsigned int u, float& a0, float& a1) {
    a0 += bf2f((unsigned short)(u & 0xffffu));
    a1 += bf2f((unsigned short)(u >> 16));
}

// --- runtime dtype sniffers ---
__global__ void k_detect_edge(const void* __restrict__ e, int* __restrict__ flag) {
    int lane = threadIdx.x;  // 64 threads
    int v = ((const int*)e)[2 * lane + 1];
    unsigned long long b = __ballot(v != 0);
    if (lane == 0) *flag = (b == 0ULL) ? 1 : 0;
}

__global__ void k_detect_dtype(const unsigned int* __restrict__ p, int* __restrict__ isbf) {
    int lane = threadIdx.x;  // 64 threads
    unsigned int u = p[lane];
    int e = (u >> 7) & 0xff;
    int sane = (e == 0) || (e >= 100 && e <= 154);
    unsigned long long b = __ballot(sane);
    if (lane == 0) *isbf = (__popcll(b) >= 48) ? 1 : 0;
}

__global__ void k_zero_i(int* __restrict__ p, int n) {
    int i = blockIdx.x * blockDim.x + threadIdx.x;
    if (i < n) p[i] = 0;
}

// --- degree count into 8 XCD-local replicas; epos = within-(replica,dst) rank ---
// r = blockIdx&7 rides the round-robin block->XCD dispatch so each replica's
// counter lines stay in one XCD's L2 (kills cross-XCD line ping-pong).
__global__ void k_count8(const void* __restrict__ e, const int* __restrict__ eflag,
                         int* __restrict__ cnt8, unsigned short* __restrict__ epos) {
    int i = blockIdx.x * blockDim.x + threadIdx.x;
    if (i >= N_EDGES) return;
    int r = blockIdx.x & 7;
    int is64 = *eflag;
    int dst = edge_at(e, is64, (long long)N_EDGES + i);
    epos[i] = (unsigned short)atomicAdd(&cnt8[r * N_NODES + dst], 1);
}

// per-dst: cnt8[r][dst] <- exclusive prefix over r; cnt[dst] <- total degree
__global__ void k_merge8(int* __restrict__ cnt8, int* __restrict__ cnt) {
    int d = blockIdx.x * blockDim.x + threadIdx.x;
    if (d >= N_NODES) return;
    int run = 0;
#pragma unroll
    for (int r = 0; r < 8; r++) {
        int v = cnt8[r * N_NODES + d];
        cnt8[r * N_NODES + d] = run;
        run += v;
    }
    cnt[d] = run;
}

// --- 3-phase exclusive scan ---
__global__ void k_scan1(const int* __restrict__ cnt, int* __restrict__ excl,
                        int* __restrict__ bsum) {
    __shared__ int s[SCAN_B];
    int tid = threadIdx.x;
    int gid = blockIdx.x * SCAN_B + tid;
    int v = (gid < N_NODES) ? cnt[gid] : 0;
    s[tid] = v;
    __syncthreads();
    for (int off = 1; off < SCAN_B; off <<= 1) {
        int t = (tid >= off) ? s[tid - off] : 0;
        __syncthreads();
        s[tid] += t;
        __syncthreads();
    }
    if (gid < N_NODES) excl[gid] = s[tid] - v;
    if (tid == SCAN_B - 1) bsum[blockIdx.x] = s[tid];
}

__global__ void k_scan2(int* __restrict__ bsum) {
    __shared__ int s[128];
    int tid = threadIdx.x;
    int v = (tid < SCAN_NB) ? bsum[tid] : 0;
    s[tid] = v;
    __syncthreads();
    for (int off = 1; off < 128; off <<= 1) {
        int t = (tid >= off) ? s[tid - off] : 0;
        __syncthreads();
        s[tid] += t;
        __syncthreads();
    }
    if (tid < SCAN_NB) bsum[tid] = s[tid] - v;
}

__global__ void k_scan3(const int* __restrict__ excl, const int* __restrict__ bsum,
                        int* __restrict__ row_start) {
    int gid = blockIdx.x * SCAN_B + threadIdx.x;
    if (gid < N_NODES) row_start[gid] = excl[gid] + bsum[blockIdx.x];
    if (gid == 0) row_start[N_NODES] = N_EDGES;
}

// pure gather->scatter, no atomics; r recomputed identically to k_count8
__global__ void k_bucket(const void* __restrict__ e, const int* __restrict__ eflag,
                         const int* __restrict__ row_start, const int* __restrict__ cnt8,
                         const unsigned short* __restrict__ epos,
                         int* __restrict__ csr_src) {
    int i = blockIdx.x * blockDim.x + threadIdx.x;
    if (i >= N_EDGES) return;
    int r = blockIdx.x & 7;
    int is64 = *eflag;
    int src = edge_at(e, is64, i);
    int dst = edge_at(e, is64, (long long)N_EDGES + i);
    csr_src[row_start[dst] + cnt8[r * N_NODES + dst] + (int)epos[i]] = src;
}

// --- convert x into Abuf cols 128..255 as bf16 ---
__global__ void k_cvt_x(const void* __restrict__ x, const int* __restrict__ dtf,
                        unsigned short* __restrict__ Abuf) {
    int idx = blockIdx.x * blockDim.x + threadIdx.x;  // one thread = 4 ch
    if (idx >= N_NODES * CH / 4) return;
    int node = idx >> 5;
    int ch = (idx & 31) * 4;
    int isbf = *dtf;
    unsigned short o[4];
    if (isbf) {
        ushort4 u = *(const ushort4*)((const unsigned short*)x + (size_t)node * CH + ch);
        o[0] = u.x; o[1] = u.y; o[2] = u.z; o[3] = u.w;
    } else {
        float4 v = *(const float4*)((const float*)x + (size_t)node * CH + ch);
        o[0] = f2bf(v.x); o[1] = f2bf(v.y); o[2] = f2bf(v.z); o[3] = f2bf(v.w);
    }
    *(ushort4*)(Abuf + (size_t)node * KTOT + CH + ch) = make_ushort4(o[0], o[1], o[2], o[3]);
}

// --- convert wl/wr into WT[n][k] bf16 (k<128 wl, k>=128 wr) ---
__global__ void k_cvt_w(const void* __restrict__ wl, const void* __restrict__ wr,
                        const int* __restrict__ dtf, unsigned short* __restrict__ WT) {
    int i = blockIdx.x * blockDim.x + threadIdx.x;  // 32768
    if (i >= KTOT * CH) return;
    int k = i >> 7;
    int n = i & 127;
    int isbf = *dtf;
    float v = (k < CH) ? ldf(wl, isbf, (size_t)k * CH + n)
                       : ldf(wr, isbf, (size_t)(k - CH) * CH + n);
    WT[(size_t)n * KTOT + k] = f2bf(v);
}

// --- gather-mean aggregation: 4 nodes/wave, 16 lanes/node, 4 edges in flight ---
__global__ __launch_bounds__(256) void k_agg(
    const int* __restrict__ row_start, const int* __restrict__ csr_src,
    const unsigned short* __restrict__ gsrc, unsigned short* __restrict__ gdst) {
    long long gt = (long long)blockIdx.x * blockDim.x + threadIdx.x;
    int node = (int)(gt >> 4);   // quarter-wave per node
    int lane = (int)(gt & 15);   // 16 lanes x 16 B = 256 B row
    if (node >= N_NODES) return;
    int beg = row_start[node];
    int end = row_start[node + 1];
    float a[8];
#pragma unroll
    for (int j = 0; j < 8; j++) a[j] = 0.f;
    int e = beg;
    for (; e + 3 < end; e += 4) {  // 4 edges in flight per node
        int s0 = csr_src[e], s1 = csr_src[e + 1];
        int s2 = csr_src[e + 2], s3 = csr_src[e + 3];
        uint4 u0 = *(const uint4*)(gsrc + (size_t)s0 * KTOT + CH + lane * 8);
        uint4 u1 = *(const uint4*)(gsrc + (size_t)s1 * KTOT + CH + lane * 8);
        uint4 u2 = *(const uint4*)(gsrc + (size_t)s2 * KTOT + CH + lane * 8);
        uint4 u3 = *(const uint4*)(gsrc + (size_t)s3 * KTOT + CH + lane * 8);
        acc_u32(u0.x, a[0], a[1]); acc_u32(u0.y, a[2], a[3]);
        acc_u32(u0.z, a[4], a[5]); acc_u32(u0.w, a[6], a[7]);
        acc_u32(u1.x, a[0], a[1]); acc_u32(u1.y, a[2], a[3]);
        acc_u32(u1.z, a[4], a[5]); acc_u32(u1.w, a[6], a[7]);
        acc_u32(u2.x, a[0], a[1]); acc_u32(u2.y, a[2], a[3]);
        acc_u32(u2.z, a[4], a[5]); acc_u32(u2.w, a[6], a[7]);
        acc_u32(u3.x, a[0], a[1]); acc_u32(u3.y, a[2], a[3]);
        acc_u32(u3.z, a[4], a[5]); acc_u32(u3.w, a[6], a[7]);
    }
    if (e + 1 < end) {
        int s0 = csr_src[e], s1 = csr_src[e + 1];
        uint4 u0 = *(const uint4*)(gsrc + (size_t)s0 * KTOT + CH + lane * 8);
        uint4 u1 = *(const uint4*)(gsrc + (size_t)s1 * KTOT + CH + lane * 8);
        acc_u32(u0.x, a[0], a[1]); acc_u32(u0.y, a[2], a[3]);
        acc_u32(u0.z, a[4], a[5]); acc_u32(u0.w, a[6], a[7]);
        acc_u32(u1.x, a[0], a[1]); acc_u32(u1.y, a[2], a[3]);
        acc_u32(u1.z, a[4], a[5]); acc_u32(u1.w, a[6], a[7]);
        e += 2;
    }
    if (e < end) {
        int s0 = csr_src[e];
        uint4 u0 = *(const uint4*)(gsrc + (size_t)s0 * KTOT + CH + lane * 8);
        acc_u32(u0.x, a[0], a[1]); acc_u32(u0.y, a[2], a[3]);
        acc_u32(u0.z, a[4], a[5]); acc_u32(u0.w, a[6], a[7]);
    }
    float rinv = 1.0f / (float)max(end - beg, 1);
    unsigned int p0 = (unsigned int)f2bf(a[0] * rinv) | ((unsigned int)f2bf(a[1] * rinv) << 16);
    unsigned int p1 = (unsigned int)f2bf(a[2] * rinv) | ((unsigned int)f2bf(a[3] * rinv) << 16);
    unsigned int p2 = (unsigned int)f2bf(a[4] * rinv) | ((unsigned int)f2bf(a[5] * rinv) << 16);
    unsigned int p3 = (unsigned int)f2bf(a[6] * rinv) | ((unsigned int)f2bf(a[7] * rinv) << 16);
    *(uint4*)(gdst + (size_t)node * KTOT + lane * 8) = make_uint4(p0, p1, p2, p3);
}

// --- MFMA GEMM: out = relu(A[m][0:256] @ WT[n][0:256]^T + bias), bf16 out ---
#define LDK 40
__global__ __launch_bounds__(256) void k_gemm_mfma(
    const unsigned short* __restrict__ Abuf, const unsigned short* __restrict__ WT,
    const void* __restrict__ bias, const int* __restrict__ dtf,
    unsigned short* __restrict__ out, int out_stride, int out_off) {
    __shared__ unsigned short As[128 * LDK];
    __shared__ unsigned short Bs[128 * LDK];
    const int t = threadIdx.x;
    const int w = t >> 6, l = t & 63;
    const int wx = w & 1, wy = w >> 1;
    const int quad = l >> 4, lrow = l & 15;
    const int row0 = blockIdx.x * 128;
    const int srow = t >> 1, shalf = t & 1;

    v4f acc[4][4];
#pragma unroll
    for (int i = 0; i < 4; i++)
#pragma unroll
        for (int j = 0; j < 4; j++) acc[i][j] = (v4f){0.f, 0.f, 0.f, 0.f};

    for (int k0 = 0; k0 < KTOT; k0 += 32) {
        int ar = row0 + srow;
        if (ar >= N_NODES) ar = N_NODES - 1;
        const uint4* ga = (const uint4*)(Abuf + (size_t)ar * KTOT + k0 + shalf * 16);
        uint4 a0 = ga[0], a1 = ga[1];
        const uint4* gb = (const uint4*)(WT + (size_t)srow * KTOT + k0 + shalf * 16);
        uint4 b0 = gb[0], b1 = gb[1];
        __syncthreads();
        *(uint4*)&As[srow * LDK + shalf * 16] = a0;
        *(uint4*)&As[srow * LDK + shalf * 16 + 8] = a1;
        *(uint4*)&Bs[srow * LDK + shalf * 16] = b0;
        *(uint4*)&Bs[srow * LDK + shalf * 16 + 8] = b1;
        __syncthreads();
        v8s af[4], bfr[4];
#pragma unroll
        for (int mi = 0; mi < 4; mi++)
            af[mi] = *(const v8s*)&As[(wy * 64 + mi * 16 + lrow) * LDK + quad * 8];
#pragma unroll
        for (int ni = 0; ni < 4; ni++)
            bfr[ni] = *(const v8s*)&Bs[(wx * 64 + ni * 16 + lrow) * LDK + quad * 8];
#pragma unroll
        for (int mi = 0; mi < 4; mi++)
#pragma unroll
            for (int ni = 0; ni < 4; ni++)
                acc[mi][ni] = __builtin_amdgcn_mfma_f32_16x16x32_bf16(
                    af[mi], bfr[ni], acc[mi][ni], 0, 0, 0);
    }
    const int isbf = *dtf;
    float bj[4];
#pragma unroll
    for (int ni = 0; ni < 4; ni++) bj[ni] = ldf(bias, isbf, wx * 64 + ni * 16 + lrow);
#pragma unroll
    for (int mi = 0; mi < 4; mi++) {
#pragma unroll
        for (int r = 0; r < 4; r++) {
            int grow = row0 + wy * 64 + mi * 16 + quad * 4 + r;
            if (grow < N_NODES) {
#pragma unroll
                for (int ni = 0; ni < 4; ni++) {
                    int col = wx * 64 + ni * 16 + lrow;
                    float v = fmaxf(acc[mi][ni][r] + bj[ni], 0.0f);
                    out[(size_t)grow * out_stride + out_off + col] = f2bf(v);
                }
            }
        }
    }
}

// --- classifier: one wave per node, bf16 h in, f32 logits out ---
__global__ void k_cls(const unsigned short* __restrict__ h, const void* __restrict__ wc,
                      const void* __restrict__ bc, const int* __restrict__ dtf,
                      float* __restrict__ out) {
    long long gt = (long long)blockIdx.x * blockDim.x + threadIdx.x;
    int node = (int)(gt >> 6);
    int lane = (int)(gt & 63);
    if (node >= N_NODES) return;
    int isbf = *dtf;
    unsigned int hu = ((const unsigned int*)(h + (size_t)node * CH))[lane];
    float h0 = bf2f((unsigned short)(hu & 0xffffu));
    float h1 = bf2f((unsigned short)(hu >> 16));
    int c0 = lane * 2;
    float a[NCLS];
#pragma unroll
    for (int j = 0; j < NCLS; j++)
        a[j] = h0 * ldf(wc, isbf, (size_t)c0 * NCLS + j) +
               h1 * ldf(wc, isbf, (size_t)(c0 + 1) * NCLS + j);
#pragma unroll
    for (int off = 32; off > 0; off >>= 1) {
#pragma unroll
        for (int j = 0; j < NCLS; j++) a[j] += __shfl_down(a[j], off);
    }
    if (lane == 0) {
#pragma unroll
        for (int j = 0; j < NCLS; j++)
            out[(size_t)node * NCLS + j] = a[j] + ldf(bc, isbf, j);
    }
}

extern "C" void kernel_launch(void* const* d_in, const int* in_sizes, int n_in,
                              void* d_out, int out_size, void* d_ws, size_t ws_size,
                              hipStream_t stream) {
    const void* x = d_in[0];
    const void* eidx = d_in[1];
    const void* w_l1 = d_in[2];
    const void* b_l1 = d_in[3];
    const void* w_r1 = d_in[4];
    const void* w_l2 = d_in[5];
    const void* b_l2 = d_in[6];
    const void* w_r2 = d_in[7];
    const void* w_cls = d_in[8];
    const void* b_cls = d_in[9];

    char* w = (char*)d_ws;
    int* eflag = (int*)w;
    int* dtf = (int*)(w + 64);
    int* cnt = (int*)(w + 4096);                             // 400 KB -> 404,096
    int* row_start = (int*)(w + 405504);                     // 400 KB -> 805,508
    int* excl = (int*)(w + 806912);                          // 400 KB -> 1,206,912
    int* bsum = (int*)(w + 1207296);                         // 512 B
    int* cnt8 = (int*)(w + 1310720);                         // 3.2 MB -> 4,510,720
    unsigned short* epos = (unsigned short*)(w + 4587520);   // 2 MB -> 6,587,520
    int* csr_src = (int*)(w + 6684672);                      // 4 MB -> 10,684,672
    unsigned short* WT1 = (unsigned short*)(w + 10747904);   // 64 KB -> 10,813,440
    unsigned short* WT2 = (unsigned short*)(w + 10813440);   // 64 KB -> 10,878,976
    unsigned short* A1 = (unsigned short*)(w + 11534336);    // 51.2 MB -> 62,734,336
    unsigned short* A2 = (unsigned short*)(w + 62914560);    // 51.2 MB -> 114,114,560 (proven fits)
    unsigned short* Hf = A1;

    hipLaunchKernelGGL(k_detect_edge, dim3(1), dim3(64), 0, stream, eidx, eflag);
    hipLaunchKernelGGL(k_detect_dtype, dim3(1), dim3(64), 0, stream,
                       (const unsigned int*)x, dtf);
    hipLaunchKernelGGL(k_zero_i, dim3((8 * N_NODES + 255) / 256), dim3(256), 0, stream,
                       cnt8, 8 * N_NODES);
    // CSR build
    hipLaunchKernelGGL(k_count8, dim3((N_EDGES + 255) / 256), dim3(256), 0, stream,
                       eidx, eflag, cnt8, epos);
    hipLaunchKernelGGL(k_merge8, dim3((N_NODES + 255) / 256), dim3(256), 0, stream,
                       cnt8, cnt);
    hipLaunchKernelGGL(k_scan1, dim3(SCAN_NB), dim3(SCAN_B), 0, stream, cnt, excl, bsum);
    hipLaunchKernelGGL(k_scan2, dim3(1), dim3(128), 0, stream, bsum);
    hipLaunchKernelGGL(k_scan3, dim3(SCAN_NB), dim3(SCAN_B), 0, stream,
                       excl, bsum, row_start);
    hipLaunchKernelGGL(k_bucket, dim3((N_EDGES + 255) / 256), dim3(256), 0, stream,
                       eidx, eflag, row_start, cnt8, epos, csr_src);
    // converts
    hipLaunchKernelGGL(k_cvt_x, dim3(N_NODES * CH / 4 / 256), dim3(256), 0, stream,
                       x, dtf, A1);
    hipLaunchKernelGGL(k_cvt_w, dim3(KTOT * CH / 256), dim3(256), 0, stream,
                       w_l1, w_r1, dtf, WT1);
    hipLaunchKernelGGL(k_cvt_w, dim3(KTOT * CH / 256), dim3(256), 0, stream,
                       w_l2, w_r2, dtf, WT2);
    // layer 1
    hipLaunchKernelGGL(k_agg, dim3(N_NODES * 16 / 256), dim3(256), 0, stream,
                       row_start, csr_src, A1, A1);
    hipLaunchKernelGGL(k_gemm_mfma, dim3((N_NODES + 127) / 128), dim3(256), 0, stream,
                       A1, WT1, b_l1, dtf, A2, KTOT, CH);
    // layer 2
    hipLaunchKernelGGL(k_agg, dim3(N_NODES * 16 / 256), dim3(256), 0, stream,
                       row_start, csr_src, A2, A2);
    hipLaunchKernelGGL(k_gemm_mfma, dim3((N_NODES + 127) / 128), dim3(256), 0, stream,
                       A2, WT2, b_l2, dtf, Hf, CH, 0);
    // classifier
    hipLaunchKernelGGL(k_cls, dim3(N_NODES * 64 / 256), dim3(256), 0, stream,
                       Hf, w_cls, b_cls, dtf, (float*)d_out);
}

// Round 8
// 330.324 us; speedup vs baseline: 6.1849x; 1.0301x over previous
//
#include <hip/hip_runtime.h>
#include <hip/hip_bf16.h>

#define N_NODES 100000
#define N_EDGES 1000000
#define CH 128
#define KTOT 256
#define NCLS 3
#define SCAN_B 1024
#define SCAN_NB ((N_NODES + SCAN_B - 1) / SCAN_B)  // 98

#define NB_CNT ((N_EDGES + 255) / 256)             // 3907
#define NB_CVTX (N_NODES * CH / 4 / 256)           // 12500
#define NB_CVTW (KTOT * CH / 256)                  // 128

typedef __attribute__((ext_vector_type(8))) short v8s;   // 8 bf16 (A/B frag)
typedef __attribute__((ext_vector_type(4))) float v4f;   // 4 f32 (C/D frag)

__device__ __forceinline__ float bf2f(unsigned short u) {
    return __uint_as_float(((unsigned int)u) << 16);
}

__device__ __forceinline__ unsigned short f2bf(float f) {  // RNE
    unsigned int u = __float_as_uint(f);
    unsigned int r = (u + 0x7fffu + ((u >> 16) & 1u)) >> 16;
    return (unsigned short)r;
}

__device__ __forceinline__ int edge_at(const void* e, int is64, long long i) {
    if (is64) return (int)((const long long*)e)[i];
    return ((const int*)e)[i];
}

__device__ __forceinline__ float ldf(const void* p, int isbf, size_t i) {
    if (isbf) return bf2f(((const unsigned short*)p)[i]);
    return ((const float*)p)[i];
}

__device__ __forceinline__ void acc_u32(unsigned int u, float& a0, float& a1) {
    a0 += bf2f((unsigned short)(u & 0xffffu));
    a1 += bf2f((unsigned short)(u >> 16));
}

// --- K0: detect dtypes + zero counters, one launch ---
__global__ void k_init(const void* __restrict__ e, const unsigned int* __restrict__ x,
                       int* __restrict__ eflag, int* __restrict__ dtf,
                       int* __restrict__ cnt) {
    int b = blockIdx.x;
    if (b == 0) {
        if (threadIdx.x < 64) {
            int v = ((const int*)e)[2 * threadIdx.x + 1];
            unsigned long long bl = __ballot(v != 0);
            if (threadIdx.x == 0) *eflag = (bl == 0ULL) ? 1 : 0;
        }
    } else if (b == 1) {
        if (threadIdx.x < 64) {
            unsigned int u = x[threadIdx.x];
            int ex = (u >> 7) & 0xff;
            int sane = (ex == 0) || (ex >= 100 && ex <= 154);
            unsigned long long bl = __ballot(sane);
            if (threadIdx.x == 0) *dtf = (__popcll(bl) >= 48) ? 1 : 0;
        }
    } else {
        int i = (b - 2) * 256 + threadIdx.x;
        if (i < N_NODES) cnt[i] = 0;
    }
}

// --- K1: fused count(+epos) || cvt_x || cvt_w1 || cvt_w2 ---
// count blocks first: their latency-bound atomic waves launch early; the
// BW-bound cvt blocks co-schedule and use the idle pipes (atomics are
// per-CU-outstanding-depth bound, so independent work rides ~free).
__global__ void k_pre(const void* __restrict__ e, const int* __restrict__ eflag,
                      const int* __restrict__ dtf,
                      int* __restrict__ cnt, unsigned short* __restrict__ epos,
                      const void* __restrict__ x, unsigned short* __restrict__ Abuf,
                      const void* __restrict__ wl1, const void* __restrict__ wr1,
                      unsigned short* __restrict__ WT1,
                      const void* __restrict__ wl2, const void* __restrict__ wr2,
                      unsigned short* __restrict__ WT2) {
    int b = blockIdx.x;
    if (b < NB_CNT) {
        int i = b * 256 + threadIdx.x;
        if (i >= N_EDGES) return;
        int is64 = *eflag;
        int dst = edge_at(e, is64, (long long)N_EDGES + i);
        epos[i] = (unsigned short)atomicAdd(&cnt[dst], 1);
    } else if (b < NB_CNT + NB_CVTX) {
        int idx = (b - NB_CNT) * 256 + threadIdx.x;
        int node = idx >> 5;
        int ch = (idx & 31) * 4;
        int isbf = *dtf;
        unsigned short o[4];
        if (isbf) {
            ushort4 u = *(const ushort4*)((const unsigned short*)x + (size_t)node * CH + ch);
            o[0] = u.x; o[1] = u.y; o[2] = u.z; o[3] = u.w;
        } else {
            float4 v = *(const float4*)((const float*)x + (size_t)node * CH + ch);
            o[0] = f2bf(v.x); o[1] = f2bf(v.y); o[2] = f2bf(v.z); o[3] = f2bf(v.w);
        }
        *(ushort4*)(Abuf + (size_t)node * KTOT + CH + ch) =
            make_ushort4(o[0], o[1], o[2], o[3]);
    } else {
        int rel = b - NB_CNT - NB_CVTX;
        const void* wl = (rel < NB_CVTW) ? wl1 : wl2;
        const void* wr = (rel < NB_CVTW) ? wr1 : wr2;
        unsigned short* WT = (rel < NB_CVTW) ? WT1 : WT2;
        int i = (rel % NB_CVTW) * 256 + threadIdx.x;
        int k = i >> 7;
        int n = i & 127;
        int isbf = *dtf;
        float v = (k < CH) ? ldf(wl, isbf, (size_t)k * CH + n)
                           : ldf(wr, isbf, (size_t)(k - CH) * CH + n);
        WT[(size_t)n * KTOT + k] = f2bf(v);
    }
}

// --- scan phase 1: per-1024-block inclusive scan -> excl + block sums ---
__global__ void k_scan1(const int* __restrict__ cnt, int* __restrict__ excl,
                        int* __restrict__ bsum) {
    __shared__ int s[SCAN_B];
    int tid = threadIdx.x;
    int gid = blockIdx.x * SCAN_B + tid;
    int v = (gid < N_NODES) ? cnt[gid] : 0;
    s[tid] = v;
    __syncthreads();
    for (int off = 1; off < SCAN_B; off <<= 1) {
        int t = (tid >= off) ? s[tid - off] : 0;
        __syncthreads();
        s[tid] += t;
        __syncthreads();
    }
    if (gid < N_NODES) excl[gid] = s[tid] - v;
    if (tid == SCAN_B - 1) bsum[blockIdx.x] = s[tid];
}

// --- scan phases 2+3 fused: each block redundantly scans the 98 bsums ---
__global__ void k_scan3b(const int* __restrict__ excl, const int* __restrict__ bsum,
                         int* __restrict__ row_start) {
    __shared__ int sb[128];
    __shared__ int spre[128];
    int tid = threadIdx.x;
    if (tid < 128) sb[tid] = (tid < SCAN_NB) ? bsum[tid] : 0;
    __syncthreads();
    if (tid < 128) {
        int run = 0;
        for (int r = 0; r < SCAN_NB; r++)
            if (r < tid) run += sb[r];
        spre[tid] = run;
    }
    __syncthreads();
    int gid = blockIdx.x * SCAN_B + tid;
    if (gid < N_NODES) row_start[gid] = excl[gid] + spre[blockIdx.x];
    if (gid == 0) row_start[N_NODES] = N_EDGES;
}

// --- bucket: pure gather->scatter, no atomics ---
__global__ void k_bucket(const void* __restrict__ e, const int* __restrict__ eflag,
                         const int* __restrict__ row_start,
                         const unsigned short* __restrict__ epos,
                         int* __restrict__ csr_src) {
    int i = blockIdx.x * blockDim.x + threadIdx.x;
    if (i >= N_EDGES) return;
    int is64 = *eflag;
    int src = edge_at(e, is64, i);
    int dst = edge_at(e, is64, (long long)N_EDGES + i);
    csr_src[row_start[dst] + (int)epos[i]] = src;
}

// --- gather-mean: 4 nodes/wave, 16 lanes/node, 8 edges in flight ---
__global__ __launch_bounds__(256) void k_agg(
    const int* __restrict__ row_start, const int* __restrict__ csr_src,
    const unsigned short* __restrict__ gsrc, unsigned short* __restrict__ gdst) {
    long long gt = (long long)blockIdx.x * blockDim.x + threadIdx.x;
    int node = (int)(gt >> 4);
    int lane = (int)(gt & 15);
    if (node >= N_NODES) return;
    int beg = row_start[node];
    int end = row_start[node + 1];
    float a[8];
#pragma unroll
    for (int j = 0; j < 8; j++) a[j] = 0.f;
    int e = beg;
    while (e + 8 <= end) {
        int s[8];
#pragma unroll
        for (int j = 0; j < 8; j++) s[j] = csr_src[e + j];
        uint4 u[8];
#pragma unroll
        for (int j = 0; j < 8; j++)
            u[j] = *(const uint4*)(gsrc + (size_t)s[j] * KTOT + CH + lane * 8);
#pragma unroll
        for (int j = 0; j < 8; j++) {
            acc_u32(u[j].x, a[0], a[1]); acc_u32(u[j].y, a[2], a[3]);
            acc_u32(u[j].z, a[4], a[5]); acc_u32(u[j].w, a[6], a[7]);
        }
        e += 8;
    }
    while (e + 2 <= end) {
        int s0 = csr_src[e], s1 = csr_src[e + 1];
        uint4 u0 = *(const uint4*)(gsrc + (size_t)s0 * KTOT + CH + lane * 8);
        uint4 u1 = *(const uint4*)(gsrc + (size_t)s1 * KTOT + CH + lane * 8);
        acc_u32(u0.x, a[0], a[1]); acc_u32(u0.y, a[2], a[3]);
        acc_u32(u0.z, a[4], a[5]); acc_u32(u0.w, a[6], a[7]);
        acc_u32(u1.x, a[0], a[1]); acc_u32(u1.y, a[2], a[3]);
        acc_u32(u1.z, a[4], a[5]); acc_u32(u1.w, a[6], a[7]);
        e += 2;
    }
    if (e < end) {
        int s0 = csr_src[e];
        uint4 u0 = *(const uint4*)(gsrc + (size_t)s0 * KTOT + CH + lane * 8);
        acc_u32(u0.x, a[0], a[1]); acc_u32(u0.y, a[2], a[3]);
        acc_u32(u0.z, a[4], a[5]); acc_u32(u0.w, a[6], a[7]);
    }
    float rinv = 1.0f / (float)max(end - beg, 1);
    unsigned int p0 = (unsigned int)f2bf(a[0] * rinv) | ((unsigned int)f2bf(a[1] * rinv) << 16);
    unsigned int p1 = (unsigned int)f2bf(a[2] * rinv) | ((unsigned int)f2bf(a[3] * rinv) << 16);
    unsigned int p2 = (unsigned int)f2bf(a[4] * rinv) | ((unsigned int)f2bf(a[5] * rinv) << 16);
    unsigned int p3 = (unsigned int)f2bf(a[6] * rinv) | ((unsigned int)f2bf(a[7] * rinv) << 16);
    *(uint4*)(gdst + (size_t)node * KTOT + lane * 8) = make_uint4(p0, p1, p2, p3);
}

// --- MFMA GEMM, double-buffered LDS: 1 barrier per K-tile ---
#define LDK 40
__global__ __launch_bounds__(256) void k_gemm_mfma(
    const unsigned short* __restrict__ Abuf, const unsigned short* __restrict__ WT,
    const void* __restrict__ bias, const int* __restrict__ dtf,
    unsigned short* __restrict__ out, int out_stride, int out_off) {
    __shared__ unsigned short As[2][128 * LDK];
    __shared__ unsigned short Bs[2][128 * LDK];
    const int t = threadIdx.x;
    const int w = t >> 6, l = t & 63;
    const int wx = w & 1, wy = w >> 1;
    const int quad = l >> 4, lrow = l & 15;
    const int row0 = blockIdx.x * 128;
    const int srow = t >> 1, shalf = t & 1;

    int ar = row0 + srow;
    if (ar >= N_NODES) ar = N_NODES - 1;  // clamp reads; stores guarded below
    const unsigned short* abase = Abuf + (size_t)ar * KTOT + shalf * 16;
    const unsigned short* bbase = WT + (size_t)srow * KTOT + shalf * 16;

    v4f acc[4][4];
#pragma unroll
    for (int i = 0; i < 4; i++)
#pragma unroll
        for (int j = 0; j < 4; j++) acc[i][j] = (v4f){0.f, 0.f, 0.f, 0.f};

    {   // prologue: stage tile 0
        uint4 a0 = *(const uint4*)abase, a1 = *(const uint4*)(abase + 8);
        uint4 b0 = *(const uint4*)bbase, b1 = *(const uint4*)(bbase + 8);
        *(uint4*)&As[0][srow * LDK + shalf * 16] = a0;
        *(uint4*)&As[0][srow * LDK + shalf * 16 + 8] = a1;
        *(uint4*)&Bs[0][srow * LDK + shalf * 16] = b0;
        *(uint4*)&Bs[0][srow * LDK + shalf * 16 + 8] = b1;
    }
#pragma unroll
    for (int k = 0; k < KTOT / 32; k++) {
        uint4 na0, na1, nb0, nb1;
        if (k < KTOT / 32 - 1) {
            na0 = *(const uint4*)(abase + (k + 1) * 32);
            na1 = *(const uint4*)(abase + (k + 1) * 32 + 8);
            nb0 = *(const uint4*)(bbase + (k + 1) * 32);
            nb1 = *(const uint4*)(bbase + (k + 1) * 32 + 8);
        }
        __syncthreads();  // buf[k&1] writes visible; prev reads of buf[nxt] done
        const int cur = k & 1, nxt = (k + 1) & 1;
        v8s af[4], bfr[4];
#pragma unroll
        for (int mi = 0; mi < 4; mi++)
            af[mi] = *(const v8s*)&As[cur][(wy * 64 + mi * 16 + lrow) * LDK + quad * 8];
#pragma unroll
        for (int ni = 0; ni < 4; ni++)
            bfr[ni] = *(const v8s*)&Bs[cur][(wx * 64 + ni * 16 + lrow) * LDK + quad * 8];
#pragma unroll
        for (int mi = 0; mi < 4; mi++)
#pragma unroll
            for (int ni = 0; ni < 4; ni++)
                acc[mi][ni] = __builtin_amdgcn_mfma_f32_16x16x32_bf16(
                    af[mi], bfr[ni], acc[mi][ni], 0, 0, 0);
        if (k < KTOT / 32 - 1) {
            *(uint4*)&As[nxt][srow * LDK + shalf * 16] = na0;
            *(uint4*)&As[nxt][srow * LDK + shalf * 16 + 8] = na1;
            *(uint4*)&Bs[nxt][srow * LDK + shalf * 16] = nb0;
            *(uint4*)&Bs[nxt][srow * LDK + shalf * 16 + 8] = nb1;
        }
    }
    const int isbf = *dtf;
    float bj[4];
#pragma unroll
    for (int ni = 0; ni < 4; ni++) bj[ni] = ldf(bias, isbf, wx * 64 + ni * 16 + lrow);
#pragma unroll
    for (int mi = 0; mi < 4; mi++) {
#pragma unroll
        for (int r = 0; r < 4; r++) {
            int grow = row0 + wy * 64 + mi * 16 + quad * 4 + r;
            if (grow < N_NODES) {
#pragma unroll
                for (int ni = 0; ni < 4; ni++) {
                    int col = wx * 64 + ni * 16 + lrow;
                    float v = fmaxf(acc[mi][ni][r] + bj[ni], 0.0f);
                    out[(size_t)grow * out_stride + out_off + col] = f2bf(v);
                }
            }
        }
    }
}

// --- classifier: one wave per node, bf16 h in, f32 logits out ---
__global__ void k_cls(const unsigned short* __restrict__ h, const void* __restrict__ wc,
                      const void* __restrict__ bc, const int* __restrict__ dtf,
                      float* __restrict__ out) {
    long long gt = (long long)blockIdx.x * blockDim.x + threadIdx.x;
    int node = (int)(gt >> 6);
    int lane = (int)(gt & 63);
    if (node >= N_NODES) return;
    int isbf = *dtf;
    unsigned int hu = ((const unsigned int*)(h + (size_t)node * CH))[lane];
    float h0 = bf2f((unsigned short)(hu & 0xffffu));
    float h1 = bf2f((unsigned short)(hu >> 16));
    int c0 = lane * 2;
    float a[NCLS];
#pragma unroll
    for (int j = 0; j < NCLS; j++)
        a[j] = h0 * ldf(wc, isbf, (size_t)c0 * NCLS + j) +
               h1 * ldf(wc, isbf, (size_t)(c0 + 1) * NCLS + j);
#pragma unroll
    for (int off = 32; off > 0; off >>= 1) {
#pragma unroll
        for (int j = 0; j < NCLS; j++) a[j] += __shfl_down(a[j], off);
    }
    if (lane == 0) {
#pragma unroll
        for (int j = 0; j < NCLS; j++)
            out[(size_t)node * NCLS + j] = a[j] + ldf(bc, isbf, j);
    }
}

extern "C" void kernel_launch(void* const* d_in, const int* in_sizes, int n_in,
                              void* d_out, int out_size, void* d_ws, size_t ws_size,
                              hipStream_t stream) {
    const void* x = d_in[0];
    const void* eidx = d_in[1];
    const void* w_l1 = d_in[2];
    const void* b_l1 = d_in[3];
    const void* w_r1 = d_in[4];
    const void* w_l2 = d_in[5];
    const void* b_l2 = d_in[6];
    const void* w_r2 = d_in[7];
    const void* w_cls = d_in[8];
    const void* b_cls = d_in[9];

    char* w = (char*)d_ws;
    int* eflag = (int*)w;
    int* dtf = (int*)(w + 64);
    int* cnt = (int*)(w + 4096);                             // 400 KB
    int* row_start = (int*)(w + 405504);                     // 400 KB
    int* excl = (int*)(w + 806912);                          // 400 KB
    int* bsum = (int*)(w + 1207296);                         // 512 B
    unsigned short* epos = (unsigned short*)(w + 2097152);   // 2 MB
    int* csr_src = (int*)(w + 4194304);                      // 4 MB -> 8,388,608
    unsigned short* WT1 = (unsigned short*)(w + 8388608);    // 64 KB
    unsigned short* WT2 = (unsigned short*)(w + 8454144);    // 64 KB
    unsigned short* A1 = (unsigned short*)(w + 11534336);    // 51.2 MB
    unsigned short* A2 = (unsigned short*)(w + 62914560);    // 51.2 MB (ends 114.1 MB, proven)
    unsigned short* Hf = A1;

    hipLaunchKernelGGL(k_init, dim3(2 + (N_NODES + 255) / 256), dim3(256), 0, stream,
                       eidx, (const unsigned int*)x, eflag, dtf, cnt);
    hipLaunchKernelGGL(k_pre, dim3(NB_CNT + NB_CVTX + 2 * NB_CVTW), dim3(256), 0, stream,
                       eidx, eflag, dtf, cnt, epos, x, A1,
                       w_l1, w_r1, WT1, w_l2, w_r2, WT2);
    hipLaunchKernelGGL(k_scan1, dim3(SCAN_NB), dim3(SCAN_B), 0, stream, cnt, excl, bsum);
    hipLaunchKernelGGL(k_scan3b, dim3(SCAN_NB), dim3(SCAN_B), 0, stream,
                       excl, bsum, row_start);
    hipLaunchKernelGGL(k_bucket, dim3(NB_CNT), dim3(256), 0, stream,
                       eidx, eflag, row_start, epos, csr_src);
    // layer 1
    hipLaunchKernelGGL(k_agg, dim3(N_NODES * 16 / 256), dim3(256), 0, stream,
                       row_start, csr_src, A1, A1);
    hipLaunchKernelGGL(k_gemm_mfma, dim3((N_NODES + 127) / 128), dim3(256), 0, stream,
                       A1, WT1, b_l1, dtf, A2, KTOT, CH);
    // layer 2
    hipLaunchKernelGGL(k_agg, dim3(N_NODES * 16 / 256), dim3(256), 0, stream,
                       row_start, csr_src, A2, A2);
    hipLaunchKernelGGL(k_gemm_mfma, dim3((N_NODES + 127) / 128), dim3(256), 0, stream,
                       A2, WT2, b_l2, dtf, Hf, CH, 0);
    // classifier
    hipLaunchKernelGGL(k_cls, dim3(N_NODES * 64 / 256), dim3(256), 0, stream,
                       Hf, w_cls, b_cls, dtf, (float*)d_out);
}

// Round 10
// 302.196 us; speedup vs baseline: 6.7606x; 1.0931x over previous
//
#include <hip/hip_runtime.h>
#include <hip/hip_bf16.h>

#define N_NODES 100000
#define N_EDGES 1000000
#define CH 128
#define KTOT 256
#define NCLS 3
#define SCAN_B 1024
#define SCAN_NB ((N_NODES + SCAN_B - 1) / SCAN_B)  // 98

#define NB_CNT ((N_EDGES + 255) / 256)             // 3907
#define NB_CVTX (N_NODES * CH / 4 / 256)           // 12500
#define NB_CVTW (KTOT * CH / 256)                  // 128
#define NB_OTHER (NB_CVTX + 2 * NB_CVTW)           // 12756
#define NB_PRE (NB_CNT + NB_OTHER)                 // 16663

typedef __attribute__((ext_vector_type(8))) short v8s;   // 8 bf16 (A/B frag)
typedef __attribute__((ext_vector_type(4))) float v4f;   // 4 f32 (C/D frag)

__device__ __forceinline__ float bf2f(unsigned short u) {
    return __uint_as_float(((unsigned int)u) << 16);
}

__device__ __forceinline__ unsigned short f2bf(float f) {  // RNE
    unsigned int u = __float_as_uint(f);
    unsigned int r = (u + 0x7fffu + ((u >> 16) & 1u)) >> 16;
    return (unsigned short)r;
}

__device__ __forceinline__ int edge_at(const void* e, int is64, long long i) {
    if (is64) return (int)((const long long*)e)[i];
    return ((const int*)e)[i];
}

__device__ __forceinline__ float ldf(const void* p, int isbf, size_t i) {
    if (isbf) return bf2f(((const unsigned short*)p)[i]);
    return ((const float*)p)[i];
}

__device__ __forceinline__ void acc_u32(unsigned int u, float& a0, float& a1) {
    a0 += bf2f((unsigned short)(u & 0xffffu));
    a1 += bf2f((unsigned short)(u >> 16));
}

// --- K0: detect dtypes + zero counters/flags ---
__global__ void k_init(const void* __restrict__ e, const unsigned int* __restrict__ x,
                       int* __restrict__ eflag, int* __restrict__ dtf,
                       int* __restrict__ cnt, int* __restrict__ done) {
    int b = blockIdx.x;
    if (b == 0) {
        if (threadIdx.x < 64) {
            int v = ((const int*)e)[2 * threadIdx.x + 1];
            unsigned long long bl = __ballot(v != 0);
            if (threadIdx.x == 0) *eflag = (bl == 0ULL) ? 1 : 0;
        } else if (threadIdx.x == 64) {
            *done = 0;
        }
    } else if (b == 1) {
        if (threadIdx.x < 64) {
            unsigned int u = x[threadIdx.x];
            int ex = (u >> 7) & 0xff;
            int sane = (ex == 0) || (ex >= 100 && ex <= 154);
            unsigned long long bl = __ballot(sane);
            if (threadIdx.x == 0) *dtf = (__popcll(bl) >= 48) ? 1 : 0;
        }
    } else {
        int i = (b - 2) * 256 + threadIdx.x;
        if (i < N_NODES) cnt[i] = 0;
    }
}

// --- K1: count(+epos) INTERLEAVED with cvt_x/cvt_w (every 4th block = count) ---
__global__ void k_pre(const void* __restrict__ e, const int* __restrict__ eflag,
                      const int* __restrict__ dtf,
                      int* __restrict__ cnt, unsigned short* __restrict__ epos,
                      const void* __restrict__ x, unsigned short* __restrict__ Abuf,
                      const void* __restrict__ wl1, const void* __restrict__ wr1,
                      unsigned short* __restrict__ WT1,
                      const void* __restrict__ wl2, const void* __restrict__ wr2,
                      unsigned short* __restrict__ WT2) {
    int b = blockIdx.x;
    int cb = (b + 3) >> 2;               // # count slots in [0,b)
    if (cb > NB_CNT) cb = NB_CNT;
    if ((b & 3) == 0 && (b >> 2) < NB_CNT) {
        int i = (b >> 2) * 256 + threadIdx.x;
        if (i >= N_EDGES) return;
        int is64 = *eflag;
        int dst = edge_at(e, is64, (long long)N_EDGES + i);
        epos[i] = (unsigned short)atomicAdd(&cnt[dst], 1);
    } else {
        int ob = b - cb;                 // other-block index
        if (ob < NB_CVTX) {
            int idx = ob * 256 + threadIdx.x;
            int node = idx >> 5;
            int ch = (idx & 31) * 4;
            int isbf = *dtf;
            unsigned short o[4];
            if (isbf) {
                ushort4 u = *(const ushort4*)((const unsigned short*)x +
                                              (size_t)node * CH + ch);
                o[0] = u.x; o[1] = u.y; o[2] = u.z; o[3] = u.w;
            } else {
                float4 v = *(const float4*)((const float*)x + (size_t)node * CH + ch);
                o[0] = f2bf(v.x); o[1] = f2bf(v.y); o[2] = f2bf(v.z); o[3] = f2bf(v.w);
            }
            *(ushort4*)(Abuf + (size_t)node * KTOT + CH + ch) =
                make_ushort4(o[0], o[1], o[2], o[3]);
        } else {
            int rel = ob - NB_CVTX;
            const void* wl = (rel < NB_CVTW) ? wl1 : wl2;
            const void* wr = (rel < NB_CVTW) ? wr1 : wr2;
            unsigned short* WT = (rel < NB_CVTW) ? WT1 : WT2;
            int i = (rel % NB_CVTW) * 256 + threadIdx.x;
            int k = i >> 7;
            int n = i & 127;
            int isbf = *dtf;
            float v = (k < CH) ? ldf(wl, isbf, (size_t)k * CH + n)
                               : ldf(wr, isbf, (size_t)(k - CH) * CH + n);
            WT[(size_t)n * KTOT + k] = f2bf(v);
        }
    }
}

// --- fused 3-phase scan with internal device barrier (98 blocks, co-resident) ---
__global__ __launch_bounds__(SCAN_B) void k_scan(
    const int* __restrict__ cnt, int* __restrict__ bsum, int* __restrict__ done,
    int* __restrict__ row_start) {
    __shared__ int s[SCAN_B];
    __shared__ int spre_sh;
    int tid = threadIdx.x;
    int gid = blockIdx.x * SCAN_B + tid;
    int v = (gid < N_NODES) ? cnt[gid] : 0;
    s[tid] = v;
    __syncthreads();
    for (int off = 1; off < SCAN_B; off <<= 1) {
        int t = (tid >= off) ? s[tid - off] : 0;
        __syncthreads();
        s[tid] += t;
        __syncthreads();
    }
    int excl_val = s[tid] - v;
    if (tid == SCAN_B - 1) {
        bsum[blockIdx.x] = s[tid];
        __threadfence();
        atomicAdd(done, 1);
    }
    if (tid == 0) {
        while (__hip_atomic_load(done, __ATOMIC_ACQUIRE, __HIP_MEMORY_SCOPE_AGENT) <
               SCAN_NB) {
        }
        __threadfence();
        int run = 0;
        for (int r = 0; r < SCAN_NB; r++) {
            if (r >= (int)blockIdx.x) break;
            run += bsum[r];
        }
        spre_sh = run;
    }
    __syncthreads();
    if (gid < N_NODES) row_start[gid] = excl_val + spre_sh;
    if (gid == 0) row_start[N_NODES] = N_EDGES;
}

// --- bucket: pure gather->scatter, no atomics ---
__global__ void k_bucket(const void* __restrict__ e, const int* __restrict__ eflag,
                         const int* __restrict__ row_start,
                         const unsigned short* __restrict__ epos,
                         int* __restrict__ csr_src) {
    int i = blockIdx.x * blockDim.x + threadIdx.x;
    if (i >= N_EDGES) return;
    int is64 = *eflag;
    int src = edge_at(e, is64, i);
    int dst = edge_at(e, is64, (long long)N_EDGES + i);
    csr_src[row_start[dst] + (int)epos[i]] = src;
}

// --- gather-mean: 4 nodes/wave, 16 lanes/node, 8 edges in flight ---
__global__ __launch_bounds__(256) void k_agg(
    const int* __restrict__ row_start, const int* __restrict__ csr_src,
    const unsigned short* __restrict__ gsrc, unsigned short* __restrict__ gdst) {
    long long gt = (long long)blockIdx.x * blockDim.x + threadIdx.x;
    int node = (int)(gt >> 4);
    int lane = (int)(gt & 15);
    if (node >= N_NODES) return;
    int beg = row_start[node];
    int end = row_start[node + 1];
    float a[8];
#pragma unroll
    for (int j = 0; j < 8; j++) a[j] = 0.f;
    int e = beg;
    while (e + 8 <= end) {
        int s[8];
#pragma unroll
        for (int j = 0; j < 8; j++) s[j] = csr_src[e + j];
        uint4 u[8];
#pragma unroll
        for (int j = 0; j < 8; j++)
            u[j] = *(const uint4*)(gsrc + (size_t)s[j] * KTOT + CH + lane * 8);
#pragma unroll
        for (int j = 0; j < 8; j++) {
            acc_u32(u[j].x, a[0], a[1]); acc_u32(u[j].y, a[2], a[3]);
            acc_u32(u[j].z, a[4], a[5]); acc_u32(u[j].w, a[6], a[7]);
        }
        e += 8;
    }
    while (e + 2 <= end) {
        int s0 = csr_src[e], s1 = csr_src[e + 1];
        uint4 u0 = *(const uint4*)(gsrc + (size_t)s0 * KTOT + CH + lane * 8);
        uint4 u1 = *(const uint4*)(gsrc + (size_t)s1 * KTOT + CH + lane * 8);
        acc_u32(u0.x, a[0], a[1]); acc_u32(u0.y, a[2], a[3]);
        acc_u32(u0.z, a[4], a[5]); acc_u32(u0.w, a[6], a[7]);
        acc_u32(u1.x, a[0], a[1]); acc_u32(u1.y, a[2], a[3]);
        acc_u32(u1.z, a[4], a[5]); acc_u32(u1.w, a[6], a[7]);
        e += 2;
    }
    if (e < end) {
        int s0 = csr_src[e];
        uint4 u0 = *(const uint4*)(gsrc + (size_t)s0 * KTOT + CH + lane * 8);
        acc_u32(u0.x, a[0], a[1]); acc_u32(u0.y, a[2], a[3]);
        acc_u32(u0.z, a[4], a[5]); acc_u32(u0.w, a[6], a[7]);
    }
    float rinv = 1.0f / (float)max(end - beg, 1);
    unsigned int p0 = (unsigned int)f2bf(a[0] * rinv) | ((unsigned int)f2bf(a[1] * rinv) << 16);
    unsigned int p1 = (unsigned int)f2bf(a[2] * rinv) | ((unsigned int)f2bf(a[3] * rinv) << 16);
    unsigned int p2 = (unsigned int)f2bf(a[4] * rinv) | ((unsigned int)f2bf(a[5] * rinv) << 16);
    unsigned int p3 = (unsigned int)f2bf(a[6] * rinv) | ((unsigned int)f2bf(a[7] * rinv) << 16);
    *(uint4*)(gdst + (size_t)node * KTOT + lane * 8) = make_uint4(p0, p1, p2, p3);
}

// --- MFMA GEMM, double-buffered; optional fused classifier epilogue ---
#define LDK 40
#define CLS_LD 130  // h2 LDS tile stride (odd dwords -> 2-way-free column reads)
__global__ __launch_bounds__(256) void k_gemm_mfma(
    const unsigned short* __restrict__ Abuf, const unsigned short* __restrict__ WT,
    const void* __restrict__ bias, const int* __restrict__ dtf,
    unsigned short* __restrict__ out, int out_stride, int out_off,
    const void* __restrict__ wcls, const void* __restrict__ bcls,
    float* __restrict__ cls_out) {
    __shared__ unsigned short smem[4 * 128 * LDK];  // As[2] | Bs[2]; reused for cls tile
    __shared__ float wcls_s[CH * NCLS];
    unsigned short* As = smem;
    unsigned short* Bs = smem + 2 * 128 * LDK;
    const int t = threadIdx.x;
    const int w = t >> 6, l = t & 63;
    const int wx = w & 1, wy = w >> 1;
    const int quad = l >> 4, lrow = l & 15;
    const int row0 = blockIdx.x * 128;
    const int srow = t >> 1, shalf = t & 1;
    const int isbf = *dtf;

    if (cls_out) {  // preload classifier weights to LDS (384 elems, 256 threads!)
        for (int i = t; i < CH * NCLS; i += 256) wcls_s[i] = ldf(wcls, isbf, i);
    }

    int ar = row0 + srow;
    if (ar >= N_NODES) ar = N_NODES - 1;  // clamp reads; stores guarded below
    const unsigned short* abase = Abuf + (size_t)ar * KTOT + shalf * 16;
    const unsigned short* bbase = WT + (size_t)srow * KTOT + shalf * 16;

    v4f acc[4][4];
#pragma unroll
    for (int i = 0; i < 4; i++)
#pragma unroll
        for (int j = 0; j < 4; j++) acc[i][j] = (v4f){0.f, 0.f, 0.f, 0.f};

    {   // prologue: stage tile 0
        uint4 a0 = *(const uint4*)abase, a1 = *(const uint4*)(abase + 8);
        uint4 b0 = *(const uint4*)bbase, b1 = *(const uint4*)(bbase + 8);
        *(uint4*)&As[srow * LDK + shalf * 16] = a0;
        *(uint4*)&As[srow * LDK + shalf * 16 + 8] = a1;
        *(uint4*)&Bs[srow * LDK + shalf * 16] = b0;
        *(uint4*)&Bs[srow * LDK + shalf * 16 + 8] = b1;
    }
#pragma unroll
    for (int k = 0; k < KTOT / 32; k++) {
        uint4 na0, na1, nb0, nb1;
        if (k < KTOT / 32 - 1) {
            na0 = *(const uint4*)(abase + (k + 1) * 32);
            na1 = *(const uint4*)(abase + (k + 1) * 32 + 8);
            nb0 = *(const uint4*)(bbase + (k + 1) * 32);
            nb1 = *(const uint4*)(bbase + (k + 1) * 32 + 8);
        }
        __syncthreads();
        const int cur = (k & 1) * 128 * LDK, nxt = ((k + 1) & 1) * 128 * LDK;
        v8s af[4], bfr[4];
#pragma unroll
        for (int mi = 0; mi < 4; mi++)
            af[mi] = *(const v8s*)&As[cur + (wy * 64 + mi * 16 + lrow) * LDK + quad * 8];
#pragma unroll
        for (int ni = 0; ni < 4; ni++)
            bfr[ni] = *(const v8s*)&Bs[cur + (wx * 64 + ni * 16 + lrow) * LDK + quad * 8];
#pragma unroll
        for (int mi = 0; mi < 4; mi++)
#pragma unroll
            for (int ni = 0; ni < 4; ni++)
                acc[mi][ni] = __builtin_amdgcn_mfma_f32_16x16x32_bf16(
                    af[mi], bfr[ni], acc[mi][ni], 0, 0, 0);
        if (k < KTOT / 32 - 1) {
            *(uint4*)&As[nxt + srow * LDK + shalf * 16] = na0;
            *(uint4*)&As[nxt + srow * LDK + shalf * 16 + 8] = na1;
            *(uint4*)&Bs[nxt + srow * LDK + shalf * 16] = nb0;
            *(uint4*)&Bs[nxt + srow * LDK + shalf * 16 + 8] = nb1;
        }
    }
    float bj[4];
#pragma unroll
    for (int ni = 0; ni < 4; ni++) bj[ni] = ldf(bias, isbf, wx * 64 + ni * 16 + lrow);

    if (!cls_out) {  // layer-1 epilogue: bias+relu, bf16 store
#pragma unroll
        for (int mi = 0; mi < 4; mi++) {
#pragma unroll
            for (int r = 0; r < 4; r++) {
                int grow = row0 + wy * 64 + mi * 16 + quad * 4 + r;
                if (grow < N_NODES) {
#pragma unroll
                    for (int ni = 0; ni < 4; ni++) {
                        int col = wx * 64 + ni * 16 + lrow;
                        float v = fmaxf(acc[mi][ni][r] + bj[ni], 0.0f);
                        out[(size_t)grow * out_stride + out_off + col] = f2bf(v);
                    }
                }
            }
        }
    } else {  // layer-2: h2 tile -> LDS (bf16, matches old Hf rounding), then logits
        __syncthreads();  // all waves done reading As/Bs; safe to reuse smem
#pragma unroll
        for (int mi = 0; mi < 4; mi++) {
#pragma unroll
            for (int r = 0; r < 4; r++) {
                int row = wy * 64 + mi * 16 + quad * 4 + r;
#pragma unroll
                for (int ni = 0; ni < 4; ni++) {
                    int col = wx * 64 + ni * 16 + lrow;
                    float v = fmaxf(acc[mi][ni][r] + bj[ni], 0.0f);
                    smem[row * CLS_LD + col] = f2bf(v);
                }
            }
        }
        __syncthreads();
        if (t < 128) {
            int grow = row0 + t;
            if (grow < N_NODES) {
                float a0 = 0.f, a1 = 0.f, a2 = 0.f;
                for (int k = 0; k < CH; k++) {
                    float h = bf2f(smem[t * CLS_LD + k]);
                    a0 += h * wcls_s[k * NCLS + 0];
                    a1 += h * wcls_s[k * NCLS + 1];
                    a2 += h * wcls_s[k * NCLS + 2];
                }
                cls_out[(size_t)grow * NCLS + 0] = a0 + ldf(bcls, isbf, 0);
                cls_out[(size_t)grow * NCLS + 1] = a1 + ldf(bcls, isbf, 1);
                cls_out[(size_t)grow * NCLS + 2] = a2 + ldf(bcls, isbf, 2);
            }
        }
    }
}

extern "C" void kernel_launch(void* const* d_in, const int* in_sizes, int n_in,
                              void* d_out, int out_size, void* d_ws, size_t ws_size,
                              hipStream_t stream) {
    const void* x = d_in[0];
    const void* eidx = d_in[1];
    const void* w_l1 = d_in[2];
    const void* b_l1 = d_in[3];
    const void* w_r1 = d_in[4];
    const void* w_l2 = d_in[5];
    const void* b_l2 = d_in[6];
    const void* w_r2 = d_in[7];
    const void* w_cls = d_in[8];
    const void* b_cls = d_in[9];

    char* w = (char*)d_ws;
    int* eflag = (int*)w;
    int* dtf = (int*)(w + 64);
    int* done = (int*)(w + 128);
    int* cnt = (int*)(w + 4096);                             // 400 KB
    int* row_start = (int*)(w + 405504);                     // 400 KB
    int* bsum = (int*)(w + 1207296);                         // 512 B
    unsigned short* epos = (unsigned short*)(w + 2097152);   // 2 MB
    int* csr_src = (int*)(w + 4194304);                      // 4 MB
    unsigned short* WT1 = (unsigned short*)(w + 8388608);    // 64 KB
    unsigned short* WT2 = (unsigned short*)(w + 8454144);    // 64 KB
    unsigned short* A1 = (unsigned short*)(w + 11534336);    // 51.2 MB
    unsigned short* A2 = (unsigned short*)(w + 62914560);    // 51.2 MB (ends 114.1 MB, proven)

    hipLaunchKernelGGL(k_init, dim3(2 + (N_NODES + 255) / 256), dim3(256), 0, stream,
                       eidx, (const unsigned int*)x, eflag, dtf, cnt, done);
    hipLaunchKernelGGL(k_pre, dim3(NB_PRE), dim3(256), 0, stream,
                       eidx, eflag, dtf, cnt, epos, x, A1,
                       w_l1, w_r1, WT1, w_l2, w_r2, WT2);
    hipLaunchKernelGGL(k_scan, dim3(SCAN_NB), dim3(SCAN_B), 0, stream,
                       cnt, bsum, done, row_start);
    hipLaunchKernelGGL(k_bucket, dim3(NB_CNT), dim3(256), 0, stream,
                       eidx, eflag, row_start, epos, csr_src);
    // layer 1
    hipLaunchKernelGGL(k_agg, dim3(N_NODES * 16 / 256), dim3(256), 0, stream,
                       row_start, csr_src, A1, A1);
    hipLaunchKernelGGL(k_gemm_mfma, dim3((N_NODES + 127) / 128), dim3(256), 0, stream,
                       A1, WT1, b_l1, dtf, A2, KTOT, CH,
                       (const void*)nullptr, (const void*)nullptr, (float*)nullptr);
    // layer 2 + fused classifier
    hipLaunchKernelGGL(k_agg, dim3(N_NODES * 16 / 256), dim3(256), 0, stream,
                       row_start, csr_src, A2, A2);
    hipLaunchKernelGGL(k_gemm_mfma, dim3((N_NODES + 127) / 128), dim3(256), 0, stream,
                       A2, WT2, b_l2, dtf, (unsigned short*)nullptr, 0, 0,
                       w_cls, b_cls, (float*)d_out);
}